// Round 1
// baseline (324.416 us; speedup 1.0000x reference)
//
#include <hip/hip_runtime.h>

typedef __attribute__((ext_vector_type(4))) float f32x4;
typedef __attribute__((ext_vector_type(8))) short s16x8;

#define GLDS(gsrc, ldst) \
  __builtin_amdgcn_global_load_lds((const __attribute__((address_space(1))) void*)(gsrc), \
                                   (__attribute__((address_space(3))) void*)(ldst), 16, 0, 0)

__device__ __forceinline__ ushort f2bf(float f) {
  union { float f; unsigned u; } x; x.f = f;
  unsigned r = (x.u + 0x7FFFu + ((x.u >> 16) & 1u)) >> 16;
  return (ushort)r;
}

// ---------------- cast f32 -> bf16 (vectorized) ----------------
__global__ __launch_bounds__(256) void castk(const float* __restrict__ in,
                                             ushort* __restrict__ outp, int n) {
  int i = (blockIdx.x * 256 + threadIdx.x) * 4;
  if (i >= n) return;
  float4 v = *(const float4*)(in + i);
  ushort4 r;
  r.x = f2bf(v.x); r.y = f2bf(v.y); r.z = f2bf(v.z); r.w = f2bf(v.w);
  *(ushort4*)(outp + i) = r;
}

// ---------------- GEMM: C[M,N] = A[M,K] * Bt[N,K]^T + bias ----------------
#define BM 128
#define BN 128
#define BK 32

__global__ __launch_bounds__(256) void gemm_bt(
    const ushort* __restrict__ A, const ushort* __restrict__ Bt,
    const float* __restrict__ bias0, const float* __restrict__ bias1,
    const float* __restrict__ bias2,
    void* __restrict__ Cout, int M, int N, int K, int outBf16)
{
  __shared__ __align__(16) ushort As[BM * BK];
  __shared__ __align__(16) ushort Bs[BN * BK];
  const int tid = threadIdx.x;
  const int w = tid >> 6, lane = tid & 63;
  const int wr = w >> 1, wc = w & 1;
  const int lrow = lane & 15, lg = lane >> 4;
  const int mblk = blockIdx.y * BM, nblk = blockIdx.x * BN;
  const int c0 = 2 * w, c1 = 2 * w + 1;
  const int ar0 = 16 * c0 + (lane >> 2), ar1 = 16 * c1 + (lane >> 2);
  const int akk = 8 * (lane & 3);
  const ushort* Ab = A + (size_t)mblk * K + akk;
  const ushort* Bb = Bt + (size_t)nblk * K + akk;
  const f32x4 zero = {0.f, 0.f, 0.f, 0.f};
  f32x4 acc[4][4];
#pragma unroll
  for (int m = 0; m < 4; m++)
#pragma unroll
    for (int n = 0; n < 4; n++) acc[m][n] = zero;

  for (int kt = 0; kt < K; kt += BK) {
    GLDS(Ab + (size_t)ar0 * K + kt, &As[512 * c0]);
    GLDS(Ab + (size_t)ar1 * K + kt, &As[512 * c1]);
    GLDS(Bb + (size_t)ar0 * K + kt, &Bs[512 * c0]);
    GLDS(Bb + (size_t)ar1 * K + kt, &Bs[512 * c1]);
    __syncthreads();
    s16x8 af[4], bfr[4];
#pragma unroll
    for (int m = 0; m < 4; m++)
      af[m] = *(const s16x8*)&As[(64 * wr + 16 * m + lrow) * BK + 8 * lg];
#pragma unroll
    for (int n = 0; n < 4; n++)
      bfr[n] = *(const s16x8*)&Bs[(64 * wc + 16 * n + lrow) * BK + 8 * lg];
#pragma unroll
    for (int m = 0; m < 4; m++)
#pragma unroll
      for (int n = 0; n < 4; n++)
        acc[m][n] = __builtin_amdgcn_mfma_f32_16x16x32_bf16(af[m], bfr[n], acc[m][n], 0, 0, 0);
    __syncthreads();
  }

#pragma unroll
  for (int m = 0; m < 4; m++) {
    const int row = mblk + 64 * wr + 16 * m + 4 * lg;
#pragma unroll
    for (int n = 0; n < 4; n++) {
      const int col = nblk + 64 * wc + 16 * n + lrow;
      float bias;
      if (bias1) bias = (col < 1024) ? bias0[col]
                       : (col < 2048 ? bias1[col - 1024] : bias2[col - 2048]);
      else bias = bias0[col];
      f32x4 v = acc[m][n];
      if (outBf16) {
        ushort* C = (ushort*)Cout;
#pragma unroll
        for (int i = 0; i < 4; i++) C[(size_t)(row + i) * N + col] = f2bf(v[i] + bias);
      } else {
        float* C = (float*)Cout;
#pragma unroll
        for (int i = 0; i < 4; i++) C[(size_t)(row + i) * N + col] = v[i] + bias;
      }
    }
  }
}

// ---------------- banded / global flash attention ----------------
// qkv: [B*2048][3072] bf16, cols 0-1023 Q, 1024-2047 K, 2048-3071 V (head h at h*64)
// outp: [B*2048][1024] bf16  (row b*2048+i, col h*64+d)
__global__ __launch_bounds__(256) void attn_kernel(const ushort* __restrict__ qkv,
                                                   ushort* __restrict__ outp)
{
  const int w = threadIdx.x >> 6, lane = threadIdx.x & 63;
  const int lrow = lane & 15, lg = lane >> 4;
  const int bx = blockIdx.x, h = blockIdx.y, b = blockIdx.z;
  const int q0 = bx * 64 + w * 16;
  const ushort* Qp = qkv + (size_t)b * 2048 * 3072 + h * 64;
  const ushort* Kp = Qp + 1024;
  const ushort* Vp = Qp + 2048;

  s16x8 qf0 = *(const s16x8*)(Qp + (size_t)(q0 + lrow) * 3072 + 8 * lg);
  s16x8 qf1 = *(const s16x8*)(Qp + (size_t)(q0 + lrow) * 3072 + 32 + 8 * lg);

  const f32x4 zero = {0.f, 0.f, 0.f, 0.f};
  f32x4 o[4];
  o[0] = zero; o[1] = zero; o[2] = zero; o[3] = zero;
  float mrun = -3e38f, lsum = 0.f;

  int kv_lo, kv_hi;
  if (h == 0) { kv_lo = 0; kv_hi = 2048; }
  else {
    kv_lo = bx * 64 - 128; if (kv_lo < 0) kv_lo = 0;
    kv_hi = bx * 64 + 192; if (kv_hi > 2048) kv_hi = 2048;
  }
  const int q_abs = q0 + lrow;

  for (int kv = kv_lo; kv < kv_hi; kv += 32) {
    s16x8 kA0 = *(const s16x8*)(Kp + (size_t)(kv + lrow) * 3072 + 8 * lg);
    s16x8 kA1 = *(const s16x8*)(Kp + (size_t)(kv + lrow) * 3072 + 32 + 8 * lg);
    s16x8 kB0 = *(const s16x8*)(Kp + (size_t)(kv + 16 + lrow) * 3072 + 8 * lg);
    s16x8 kB1 = *(const s16x8*)(Kp + (size_t)(kv + 16 + lrow) * 3072 + 32 + 8 * lg);

    f32x4 sA = __builtin_amdgcn_mfma_f32_16x16x32_bf16(kA0, qf0, zero, 0, 0, 0);
    sA = __builtin_amdgcn_mfma_f32_16x16x32_bf16(kA1, qf1, sA, 0, 0, 0);
    f32x4 sB = __builtin_amdgcn_mfma_f32_16x16x32_bf16(kB0, qf0, zero, 0, 0, 0);
    sB = __builtin_amdgcn_mfma_f32_16x16x32_bf16(kB1, qf1, sB, 0, 0, 0);

    float pA[4], pB[4];
    float rowmax = -3e38f;
#pragma unroll
    for (int i = 0; i < 4; i++) {
      int kaA = kv + 4 * lg + i;
      int dq = q_abs - kaA;
      bool alA = (h == 0) || (dq <= 128 && dq >= -128);
      float va = alA ? sA[i] * 0.125f : -3e38f;
      pA[i] = va; rowmax = fmaxf(rowmax, va);
      int kaB = kaA + 16;
      int dqb = q_abs - kaB;
      bool alB = (h == 0) || (dqb <= 128 && dqb >= -128);
      float vb = alB ? sB[i] * 0.125f : -3e38f;
      pB[i] = vb; rowmax = fmaxf(rowmax, vb);
    }
    rowmax = fmaxf(rowmax, __shfl_xor(rowmax, 16));
    rowmax = fmaxf(rowmax, __shfl_xor(rowmax, 32));
    float mnew = fmaxf(mrun, rowmax);
    float alpha = __expf(mrun - mnew);
    mrun = mnew;
    float rsum = 0.f;
#pragma unroll
    for (int i = 0; i < 4; i++) {
      pA[i] = (pA[i] > -1e37f) ? __expf(pA[i] - mnew) : 0.f;
      pB[i] = (pB[i] > -1e37f) ? __expf(pB[i] - mnew) : 0.f;
      rsum += pA[i] + pB[i];
    }
    rsum += __shfl_xor(rsum, 16);
    rsum += __shfl_xor(rsum, 32);
    lsum = lsum * alpha + rsum;

    float a0 = __shfl(alpha, 4 * lg + 0);
    float a1 = __shfl(alpha, 4 * lg + 1);
    float a2 = __shfl(alpha, 4 * lg + 2);
    float a3 = __shfl(alpha, 4 * lg + 3);
#pragma unroll
    for (int c = 0; c < 4; c++) {
      o[c][0] *= a0; o[c][1] *= a1; o[c][2] *= a2; o[c][3] *= a3;
    }

    // redistribute P (held as S^T fragments) into 16x16x32 A-fragment layout
    s16x8 paf;
#pragma unroll
    for (int j = 0; j < 8; j++) {
      int src = 16 * (2 * (lg & 1) + (j >> 2)) + lrow;
      float vA = __shfl(pA[j & 3], src);
      float vB = __shfl(pB[j & 3], src);
      float pv = (lg >= 2) ? vB : vA;
      paf[j] = (short)f2bf(pv);
    }

#pragma unroll
    for (int c = 0; c < 4; c++) {
      s16x8 vf;
#pragma unroll
      for (int j = 0; j < 8; j++)
        vf[j] = (short)Vp[(size_t)(kv + 8 * lg + j) * 3072 + 16 * c + lrow];
      o[c] = __builtin_amdgcn_mfma_f32_16x16x32_bf16(paf, vf, o[c], 0, 0, 0);
    }
  }

  float li0 = 1.f / __shfl(lsum, 4 * lg + 0);
  float li1 = 1.f / __shfl(lsum, 4 * lg + 1);
  float li2 = 1.f / __shfl(lsum, 4 * lg + 2);
  float li3 = 1.f / __shfl(lsum, 4 * lg + 3);
  size_t orow = (size_t)(b * 2048 + q0 + 4 * lg);
#pragma unroll
  for (int c = 0; c < 4; c++) {
    outp[(orow + 0) * 1024 + h * 64 + 16 * c + lrow] = f2bf(o[c][0] * li0);
    outp[(orow + 1) * 1024 + h * 64 + 16 * c + lrow] = f2bf(o[c][1] * li1);
    outp[(orow + 2) * 1024 + h * 64 + 16 * c + lrow] = f2bf(o[c][2] * li2);
    outp[(orow + 3) * 1024 + h * 64 + 16 * c + lrow] = f2bf(o[c][3] * li3);
  }
}

// ---------------- launch ----------------
extern "C" void kernel_launch(void* const* d_in, const int* in_sizes, int n_in,
                              void* d_out, int out_size, void* d_ws, size_t ws_size,
                              hipStream_t stream) {
  const float* x  = (const float*)d_in[0];
  const float* wq = (const float*)d_in[1];
  const float* bq = (const float*)d_in[2];
  const float* wk = (const float*)d_in[3];
  const float* bk = (const float*)d_in[4];
  const float* wv = (const float*)d_in[5];
  const float* bv = (const float*)d_in[6];
  const float* wo = (const float*)d_in[7];
  const float* bo = (const float*)d_in[8];

  char* ws = (char*)d_ws;
  ushort* xb    = (ushort*)(ws);                 // 8192x1024 bf16 = 16 MB
  ushort* wqkvb = (ushort*)(ws + 16777216);      // 3072x1024 bf16 =  6 MB
  ushort* wob   = (ushort*)(ws + 23068672);      // 1024x1024 bf16 =  2 MB
  ushort* qkvb  = (ushort*)(ws + 25165824);      // 8192x3072 bf16 = 48 MB
  ushort* attno = (ushort*)(ws + 75497472);      // 8192x1024 bf16 = 16 MB

  castk<<<8192, 256, 0, stream>>>(x, xb, 8388608);
  castk<<<1024, 256, 0, stream>>>(wq, wqkvb, 1048576);
  castk<<<1024, 256, 0, stream>>>(wk, wqkvb + 1048576, 1048576);
  castk<<<1024, 256, 0, stream>>>(wv, wqkvb + 2097152, 1048576);
  castk<<<1024, 256, 0, stream>>>(wo, wob, 1048576);

  // QKV projection: [8192,3072] = xb * wqkvb^T + (bq|bk|bv)
  gemm_bt<<<dim3(24, 64), 256, 0, stream>>>(xb, wqkvb, bq, bk, bv,
                                            (void*)qkvb, 8192, 3072, 1024, 1);

  attn_kernel<<<dim3(32, 16, 4), 256, 0, stream>>>(qkvb, attno);

  // output projection: d_out[8192,1024] = attno * wob^T + bo (f32 out)
  gemm_bt<<<dim3(8, 64), 256, 0, stream>>>(attno, wob, bo, nullptr, nullptr,
                                           (void*)d_out, 8192, 1024, 1024, 0);
}

// Round 2
// 225.934 us; speedup vs baseline: 1.4359x; 1.4359x over previous
//
#include <hip/hip_runtime.h>

typedef __attribute__((ext_vector_type(4))) float f32x4;
typedef __attribute__((ext_vector_type(8))) short s16x8;

#define GLDS(gsrc, ldst) \
  __builtin_amdgcn_global_load_lds((const __attribute__((address_space(1))) void*)(gsrc), \
                                   (__attribute__((address_space(3))) void*)(ldst), 16, 0, 0)

__device__ __forceinline__ ushort f2bf(float f) {
  union { float f; unsigned u; } x; x.f = f;
  unsigned r = (x.u + 0x7FFFu + ((x.u >> 16) & 1u)) >> 16;
  return (ushort)r;
}

// ---------------- cast f32 -> bf16 (vectorized) ----------------
__global__ __launch_bounds__(256) void castk(const float* __restrict__ in,
                                             ushort* __restrict__ outp, int n) {
  int i = (blockIdx.x * 256 + threadIdx.x) * 4;
  if (i >= n) return;
  float4 v = *(const float4*)(in + i);
  ushort4 r;
  r.x = f2bf(v.x); r.y = f2bf(v.y); r.z = f2bf(v.z); r.w = f2bf(v.w);
  *(ushort4*)(outp + i) = r;
}

// ---------------- GEMM: C[M,N] = A[M,K] * Bt[N,K]^T + bias ----------------
#define BM 128
#define BN 128
#define BK 32

__global__ __launch_bounds__(256) void gemm_bt(
    const ushort* __restrict__ A, const ushort* __restrict__ Bt,
    const float* __restrict__ bias0, const float* __restrict__ bias1,
    const float* __restrict__ bias2,
    void* __restrict__ Cout, int M, int N, int K, int outBf16)
{
  __shared__ __align__(16) ushort As[BM * BK];
  __shared__ __align__(16) ushort Bs[BN * BK];
  const int tid = threadIdx.x;
  const int w = tid >> 6, lane = tid & 63;
  const int wr = w >> 1, wc = w & 1;
  const int lrow = lane & 15, lg = lane >> 4;
  const int mblk = blockIdx.y * BM, nblk = blockIdx.x * BN;
  const int c0 = 2 * w, c1 = 2 * w + 1;
  const int ar0 = 16 * c0 + (lane >> 2), ar1 = 16 * c1 + (lane >> 2);
  const int akk = 8 * (lane & 3);
  const ushort* Ab = A + (size_t)mblk * K + akk;
  const ushort* Bb = Bt + (size_t)nblk * K + akk;
  const f32x4 zero = {0.f, 0.f, 0.f, 0.f};
  f32x4 acc[4][4];
#pragma unroll
  for (int m = 0; m < 4; m++)
#pragma unroll
    for (int n = 0; n < 4; n++) acc[m][n] = zero;

  for (int kt = 0; kt < K; kt += BK) {
    GLDS(Ab + (size_t)ar0 * K + kt, &As[512 * c0]);
    GLDS(Ab + (size_t)ar1 * K + kt, &As[512 * c1]);
    GLDS(Bb + (size_t)ar0 * K + kt, &Bs[512 * c0]);
    GLDS(Bb + (size_t)ar1 * K + kt, &Bs[512 * c1]);
    __syncthreads();
    s16x8 af[4], bfr[4];
#pragma unroll
    for (int m = 0; m < 4; m++)
      af[m] = *(const s16x8*)&As[(64 * wr + 16 * m + lrow) * BK + 8 * lg];
#pragma unroll
    for (int n = 0; n < 4; n++)
      bfr[n] = *(const s16x8*)&Bs[(64 * wc + 16 * n + lrow) * BK + 8 * lg];
#pragma unroll
    for (int m = 0; m < 4; m++)
#pragma unroll
      for (int n = 0; n < 4; n++)
        acc[m][n] = __builtin_amdgcn_mfma_f32_16x16x32_bf16(af[m], bfr[n], acc[m][n], 0, 0, 0);
    __syncthreads();
  }

#pragma unroll
  for (int m = 0; m < 4; m++) {
    const int row = mblk + 64 * wr + 16 * m + 4 * lg;
#pragma unroll
    for (int n = 0; n < 4; n++) {
      const int col = nblk + 64 * wc + 16 * n + lrow;
      float bias;
      if (bias1) bias = (col < 1024) ? bias0[col]
                       : (col < 2048 ? bias1[col - 1024] : bias2[col - 2048]);
      else bias = bias0[col];
      f32x4 v = acc[m][n];
      if (outBf16) {
        ushort* C = (ushort*)Cout;
#pragma unroll
        for (int i = 0; i < 4; i++) C[(size_t)(row + i) * N + col] = f2bf(v[i] + bias);
      } else {
        float* C = (float*)Cout;
#pragma unroll
        for (int i = 0; i < 4; i++) C[(size_t)(row + i) * N + col] = v[i] + bias;
      }
    }
  }
}

// ---------------- banded / global flash attention (LDS-tiled) ----------------
// qkv: [B*2048][3072] bf16, cols 0-1023 Q, 1024-2047 K, 2048-3071 V (head h at h*64)
// outp: [B*2048][1024] bf16
// Block: 256 thr (4 waves), 64 q rows (wave w -> q0 = bx*64 + w*16), KV tiles of 64.
// K LDS layout:  Ks[r][d] at ushort idx r*64 + ((( (d>>3) ^ (r&7) )&7)<<3) + (d&7)
// V LDS layout (transposed): Vt[d][r] at d*64 + ((( (r>>3) ^ (d&7) ^ (d>>3) )&7)<<3) + (r&7)
__global__ __launch_bounds__(256) void attn_kernel(const ushort* __restrict__ qkv,
                                                   ushort* __restrict__ outp)
{
  __shared__ __align__(16) ushort Ks[64 * 64];
  __shared__ __align__(16) ushort Vt[64 * 64];
  __shared__ __align__(16) ushort Ps[4][16 * 40];   // per-wave P buffer, stride 40

  const int tid = threadIdx.x;
  const int w = tid >> 6, lane = tid & 63;
  const int lrow = lane & 15, lg = lane >> 4;
  const int bx = blockIdx.x, h = blockIdx.y, b = blockIdx.z;
  const int q0 = bx * 64 + w * 16;
  const ushort* Qp = qkv + (size_t)b * 2048 * 3072 + h * 64;
  const ushort* Kp = Qp + 1024;
  const ushort* Vp = Qp + 2048;

  s16x8 qf0 = *(const s16x8*)(Qp + (size_t)(q0 + lrow) * 3072 + 8 * lg);
  s16x8 qf1 = *(const s16x8*)(Qp + (size_t)(q0 + lrow) * 3072 + 32 + 8 * lg);

  const f32x4 zero = {0.f, 0.f, 0.f, 0.f};
  f32x4 o[4];
  o[0] = zero; o[1] = zero; o[2] = zero; o[3] = zero;
  float mrun = -3e38f, lsum = 0.f;

  int kv_lo, kv_hi;
  if (h == 0) { kv_lo = 0; kv_hi = 2048; }
  else {
    kv_lo = bx * 64 - 128; if (kv_lo < 0) kv_lo = 0;
    kv_hi = bx * 64 + 192; if (kv_hi > 2048) kv_hi = 2048;
  }
  const int q_abs = q0 + lrow;

  // staging assignments
  const int sp = tid >> 3;      // 0..31 : V row-pair index (rows 2sp, 2sp+1)
  const int sg = tid & 7;       // 0..7  : 8-ushort chunk within row
  const int kr0 = tid >> 3;     // K rows 0..31 (issue 0), +32 (issue 1)
  const int kc = tid & 7;       // K dest chunk
  const int vx = (lrow & 7) ^ (lrow >> 3);

  for (int kv = kv_lo; kv < kv_hi; kv += 64) {
    // V rows -> regs (coalesced) before the barrier
    const ushort* vrow = Vp + (size_t)(kv + 2 * sp) * 3072 + 8 * sg;
    s16x8 vlo = *(const s16x8*)vrow;
    s16x8 vhi = *(const s16x8*)(vrow + 3072);

    __syncthreads();   // previous tile fully consumed

    // K -> LDS direct (source chunk pre-swizzled so LDS stays linear)
    GLDS(Kp + (size_t)(kv + kr0) * 3072 + 8 * (kc ^ (kr0 & 7)), &Ks[w * 512]);
    GLDS(Kp + (size_t)(kv + 32 + kr0) * 3072 + 8 * (kc ^ (kr0 & 7)), &Ks[2048 + w * 512]);

    // V transpose-write (packed pairs, swizzled)
#pragma unroll
    for (int j = 0; j < 8; j++) {
      const int d = 8 * sg + j;
      const int r = 2 * sp;
      uint pk = (uint)(ushort)vlo[j] | ((uint)(ushort)vhi[j] << 16);
      *(uint*)&Vt[d * 64 + ((((r >> 3) ^ j ^ sg) & 7) << 3) + (r & 7)] = pk;
    }
    __syncthreads();   // tile staged

#pragma unroll
    for (int s = 0; s < 2; s++) {
      const int kb = kv + 32 * s;
      const int rs = 32 * s;
      s16x8 kA0 = *(const s16x8*)&Ks[(rs + lrow) * 64      + ((( lg      ^ (lrow & 7)) & 7) << 3)];
      s16x8 kA1 = *(const s16x8*)&Ks[(rs + lrow) * 64      + ((((4 + lg) ^ (lrow & 7)) & 7) << 3)];
      s16x8 kB0 = *(const s16x8*)&Ks[(rs + 16 + lrow) * 64 + ((( lg      ^ (lrow & 7)) & 7) << 3)];
      s16x8 kB1 = *(const s16x8*)&Ks[(rs + 16 + lrow) * 64 + ((((4 + lg) ^ (lrow & 7)) & 7) << 3)];

      f32x4 sA = __builtin_amdgcn_mfma_f32_16x16x32_bf16(kA0, qf0, zero, 0, 0, 0);
      sA = __builtin_amdgcn_mfma_f32_16x16x32_bf16(kA1, qf1, sA, 0, 0, 0);
      f32x4 sB = __builtin_amdgcn_mfma_f32_16x16x32_bf16(kB0, qf0, zero, 0, 0, 0);
      sB = __builtin_amdgcn_mfma_f32_16x16x32_bf16(kB1, qf1, sB, 0, 0, 0);

      float pA[4], pB[4];
      float rowmax = -3e38f;
#pragma unroll
      for (int i = 0; i < 4; i++) {
        int kaA = kb + 4 * lg + i;
        int dq = q_abs - kaA;
        bool alA = (h == 0) || (dq <= 128 && dq >= -128);
        float va = alA ? sA[i] * 0.125f : -3e38f;
        pA[i] = va; rowmax = fmaxf(rowmax, va);
        int kaB = kaA + 16;
        int dqb = q_abs - kaB;
        bool alB = (h == 0) || (dqb <= 128 && dqb >= -128);
        float vb = alB ? sB[i] * 0.125f : -3e38f;
        pB[i] = vb; rowmax = fmaxf(rowmax, vb);
      }
      rowmax = fmaxf(rowmax, __shfl_xor(rowmax, 16));
      rowmax = fmaxf(rowmax, __shfl_xor(rowmax, 32));
      float mnew = fmaxf(mrun, rowmax);
      float alpha = __expf(mrun - mnew);
      mrun = mnew;
      float rsum = 0.f;
#pragma unroll
      for (int i = 0; i < 4; i++) {
        pA[i] = (pA[i] > -1e37f) ? __expf(pA[i] - mnew) : 0.f;
        pB[i] = (pB[i] > -1e37f) ? __expf(pB[i] - mnew) : 0.f;
        rsum += pA[i] + pB[i];
      }
      rsum += __shfl_xor(rsum, 16);
      rsum += __shfl_xor(rsum, 32);
      lsum = lsum * alpha + rsum;

      float a0 = __shfl(alpha, 4 * lg + 0);
      float a1 = __shfl(alpha, 4 * lg + 1);
      float a2 = __shfl(alpha, 4 * lg + 2);
      float a3 = __shfl(alpha, 4 * lg + 3);
#pragma unroll
      for (int c = 0; c < 4; c++) {
        o[c][0] *= a0; o[c][1] *= a1; o[c][2] *= a2; o[c][3] *= a3;
      }

      // P -> per-wave LDS buffer, read back in A-fragment layout
      {
        ushort* P = &Ps[w][lrow * 40];
        *(uint*)&P[4 * lg]      = (uint)f2bf(pA[0]) | ((uint)f2bf(pA[1]) << 16);
        *(uint*)&P[4 * lg + 2]  = (uint)f2bf(pA[2]) | ((uint)f2bf(pA[3]) << 16);
        *(uint*)&P[16 + 4 * lg] = (uint)f2bf(pB[0]) | ((uint)f2bf(pB[1]) << 16);
        *(uint*)&P[18 + 4 * lg] = (uint)f2bf(pB[2]) | ((uint)f2bf(pB[3]) << 16);
      }
      s16x8 paf = *(const s16x8*)&Ps[w][lrow * 40 + 8 * lg];

#pragma unroll
      for (int c = 0; c < 4; c++) {
        const int d = 16 * c + lrow;
        s16x8 vf = *(const s16x8*)&Vt[d * 64 + ((((4 * s + lg) ^ vx ^ (2 * c)) & 7) << 3)];
        o[c] = __builtin_amdgcn_mfma_f32_16x16x32_bf16(paf, vf, o[c], 0, 0, 0);
      }
    }
  }

  float li0 = 1.f / __shfl(lsum, 4 * lg + 0);
  float li1 = 1.f / __shfl(lsum, 4 * lg + 1);
  float li2 = 1.f / __shfl(lsum, 4 * lg + 2);
  float li3 = 1.f / __shfl(lsum, 4 * lg + 3);
  size_t orow = (size_t)(b * 2048 + q0 + 4 * lg);
#pragma unroll
  for (int c = 0; c < 4; c++) {
    outp[(orow + 0) * 1024 + h * 64 + 16 * c + lrow] = f2bf(o[c][0] * li0);
    outp[(orow + 1) * 1024 + h * 64 + 16 * c + lrow] = f2bf(o[c][1] * li1);
    outp[(orow + 2) * 1024 + h * 64 + 16 * c + lrow] = f2bf(o[c][2] * li2);
    outp[(orow + 3) * 1024 + h * 64 + 16 * c + lrow] = f2bf(o[c][3] * li3);
  }
}

// ---------------- launch ----------------
extern "C" void kernel_launch(void* const* d_in, const int* in_sizes, int n_in,
                              void* d_out, int out_size, void* d_ws, size_t ws_size,
                              hipStream_t stream) {
  const float* x  = (const float*)d_in[0];
  const float* wq = (const float*)d_in[1];
  const float* bq = (const float*)d_in[2];
  const float* wk = (const float*)d_in[3];
  const float* bk = (const float*)d_in[4];
  const float* wv = (const float*)d_in[5];
  const float* bv = (const float*)d_in[6];
  const float* wo = (const float*)d_in[7];
  const float* bo = (const float*)d_in[8];

  char* ws = (char*)d_ws;
  ushort* xb    = (ushort*)(ws);                 // 8192x1024 bf16 = 16 MB
  ushort* wqkvb = (ushort*)(ws + 16777216);      // 3072x1024 bf16 =  6 MB
  ushort* wob   = (ushort*)(ws + 23068672);      // 1024x1024 bf16 =  2 MB
  ushort* qkvb  = (ushort*)(ws + 25165824);      // 8192x3072 bf16 = 48 MB
  ushort* attno = (ushort*)(ws + 75497472);      // 8192x1024 bf16 = 16 MB

  castk<<<8192, 256, 0, stream>>>(x, xb, 8388608);
  castk<<<1024, 256, 0, stream>>>(wq, wqkvb, 1048576);
  castk<<<1024, 256, 0, stream>>>(wk, wqkvb + 1048576, 1048576);
  castk<<<1024, 256, 0, stream>>>(wv, wqkvb + 2097152, 1048576);
  castk<<<1024, 256, 0, stream>>>(wo, wob, 1048576);

  // QKV projection: [8192,3072] = xb * wqkvb^T + (bq|bk|bv)
  gemm_bt<<<dim3(24, 64), 256, 0, stream>>>(xb, wqkvb, bq, bk, bv,
                                            (void*)qkvb, 8192, 3072, 1024, 1);

  attn_kernel<<<dim3(32, 16, 4), 256, 0, stream>>>(qkvb, attno);

  // output projection: d_out[8192,1024] = attno * wob^T + bo (f32 out)
  gemm_bt<<<dim3(8, 64), 256, 0, stream>>>(attno, wob, bo, nullptr, nullptr,
                                           (void*)d_out, 8192, 1024, 1024, 0);
}

// Round 3
// 183.387 us; speedup vs baseline: 1.7690x; 1.2320x over previous
//
#include <hip/hip_runtime.h>

typedef __attribute__((ext_vector_type(4))) float f32x4;
typedef __attribute__((ext_vector_type(8))) short s16x8;

#define GLDS(gsrc, ldst) \
  __builtin_amdgcn_global_load_lds((const __attribute__((address_space(1))) void*)(gsrc), \
                                   (__attribute__((address_space(3))) void*)(ldst), 16, 0, 0)

__device__ __forceinline__ ushort f2bf(float f) {
  union { float f; unsigned u; } x; x.f = f;
  unsigned r = (x.u + 0x7FFFu + ((x.u >> 16) & 1u)) >> 16;
  return (ushort)r;
}

// ---------------- cast f32 -> bf16 (vectorized) ----------------
__global__ __launch_bounds__(256) void castk(const float* __restrict__ in,
                                             ushort* __restrict__ outp, int n) {
  int i = (blockIdx.x * 256 + threadIdx.x) * 4;
  if (i >= n) return;
  float4 v = *(const float4*)(in + i);
  ushort4 r;
  r.x = f2bf(v.x); r.y = f2bf(v.y); r.z = f2bf(v.z); r.w = f2bf(v.w);
  *(ushort4*)(outp + i) = r;
}

// fused 4-weight cast: each weight is 1024x1024 f32 -> bf16 (1024 blocks each)
__global__ __launch_bounds__(256) void castw(const float* __restrict__ w0, const float* __restrict__ w1,
                                             const float* __restrict__ w2, const float* __restrict__ w3,
                                             ushort* __restrict__ o0, ushort* __restrict__ o1,
                                             ushort* __restrict__ o2, ushort* __restrict__ o3) {
  int bid = blockIdx.x;
  int sel = bid >> 10;
  const float* in = (sel == 0) ? w0 : (sel == 1) ? w1 : (sel == 2) ? w2 : w3;
  ushort* outp    = (sel == 0) ? o0 : (sel == 1) ? o1 : (sel == 2) ? o2 : o3;
  int i = ((bid & 1023) * 256 + threadIdx.x) * 4;
  float4 v = *(const float4*)(in + i);
  ushort4 r;
  r.x = f2bf(v.x); r.y = f2bf(v.y); r.z = f2bf(v.z); r.w = f2bf(v.w);
  *(ushort4*)(outp + i) = r;
}

// ---------------- GEMM: C[M,N] = A[M,K] * Bt[N,K]^T + bias ----------------
#define BM 128
#define BN 128
#define BK 32

__global__ __launch_bounds__(256) void gemm_bt(
    const ushort* __restrict__ A, const ushort* __restrict__ Bt,
    const float* __restrict__ bias0, const float* __restrict__ bias1,
    const float* __restrict__ bias2,
    void* __restrict__ Cout, int M, int N, int K, int outBf16)
{
  __shared__ __align__(16) ushort As[BM * BK];
  __shared__ __align__(16) ushort Bs[BN * BK];
  const int tid = threadIdx.x;
  const int w = tid >> 6, lane = tid & 63;
  const int wr = w >> 1, wc = w & 1;
  const int lrow = lane & 15, lg = lane >> 4;
  const int mblk = blockIdx.y * BM, nblk = blockIdx.x * BN;
  const int c0 = 2 * w, c1 = 2 * w + 1;
  const int ar0 = 16 * c0 + (lane >> 2), ar1 = 16 * c1 + (lane >> 2);
  const int akk = 8 * (lane & 3);
  const ushort* Ab = A + (size_t)mblk * K + akk;
  const ushort* Bb = Bt + (size_t)nblk * K + akk;
  const f32x4 zero = {0.f, 0.f, 0.f, 0.f};
  f32x4 acc[4][4];
#pragma unroll
  for (int m = 0; m < 4; m++)
#pragma unroll
    for (int n = 0; n < 4; n++) acc[m][n] = zero;

  for (int kt = 0; kt < K; kt += BK) {
    GLDS(Ab + (size_t)ar0 * K + kt, &As[512 * c0]);
    GLDS(Ab + (size_t)ar1 * K + kt, &As[512 * c1]);
    GLDS(Bb + (size_t)ar0 * K + kt, &Bs[512 * c0]);
    GLDS(Bb + (size_t)ar1 * K + kt, &Bs[512 * c1]);
    __syncthreads();
    s16x8 af[4], bfr[4];
#pragma unroll
    for (int m = 0; m < 4; m++)
      af[m] = *(const s16x8*)&As[(64 * wr + 16 * m + lrow) * BK + 8 * lg];
#pragma unroll
    for (int n = 0; n < 4; n++)
      bfr[n] = *(const s16x8*)&Bs[(64 * wc + 16 * n + lrow) * BK + 8 * lg];
#pragma unroll
    for (int m = 0; m < 4; m++)
#pragma unroll
      for (int n = 0; n < 4; n++)
        acc[m][n] = __builtin_amdgcn_mfma_f32_16x16x32_bf16(af[m], bfr[n], acc[m][n], 0, 0, 0);
    __syncthreads();
  }

#pragma unroll
  for (int m = 0; m < 4; m++) {
    const int row = mblk + 64 * wr + 16 * m + 4 * lg;
#pragma unroll
    for (int n = 0; n < 4; n++) {
      const int col = nblk + 64 * wc + 16 * n + lrow;
      float bias;
      if (bias1) bias = (col < 1024) ? bias0[col]
                       : (col < 2048 ? bias1[col - 1024] : bias2[col - 2048]);
      else bias = bias0[col];
      f32x4 v = acc[m][n];
      if (outBf16) {
        ushort* C = (ushort*)Cout;
#pragma unroll
        for (int i = 0; i < 4; i++) C[(size_t)(row + i) * N + col] = f2bf(v[i] + bias);
      } else {
        float* C = (float*)Cout;
#pragma unroll
        for (int i = 0; i < 4; i++) C[(size_t)(row + i) * N + col] = v[i] + bias;
      }
    }
  }
}

// ---------------- banded / global flash attention (balanced) ----------------
// Grid: 2944 blocks. bid<1024: global-head partials (chunk-major, 8 chunks x 128 q-tiles).
// bid>=1024: band heads (head-major, 15 x 128 q-tiles), direct output.
__global__ __launch_bounds__(256) void attn_kernel(const ushort* __restrict__ qkv,
                                                   ushort* __restrict__ outp,
                                                   float* __restrict__ oPart,
                                                   float* __restrict__ mPart,
                                                   float* __restrict__ lPart)
{
  __shared__ __align__(16) ushort Ks[64 * 64];
  __shared__ __align__(16) ushort Vt[64 * 64];
  __shared__ __align__(16) ushort Ps[4][16 * 40];

  const int tid = threadIdx.x;
  const int w = tid >> 6, lane = tid & 63;
  const int lrow = lane & 15, lg = lane >> 4;

  // bijective XCD-chunk swizzle (2944 = 8 * 368)
  const int bid = (blockIdx.x & 7) * 368 + (blockIdx.x >> 3);
  int h, b, bx, kv_lo, kv_hi, chunk = 0;
  bool isGlobal;
  if (bid < 1024) {
    isGlobal = true; h = 0;
    chunk = bid >> 7;
    int qb = bid & 127;
    b = qb >> 5; bx = qb & 31;
    kv_lo = chunk * 256; kv_hi = kv_lo + 256;
  } else {
    isGlobal = false;
    int t = bid - 1024;
    h = 1 + (t >> 7);
    int qb = t & 127;
    b = qb >> 5; bx = qb & 31;
    kv_lo = bx * 64 - 128; if (kv_lo < 0) kv_lo = 0;
    kv_hi = bx * 64 + 192; if (kv_hi > 2048) kv_hi = 2048;
  }
  const int q0b = bx * 64;
  const int q0 = q0b + w * 16;
  const ushort* Qp = qkv + (size_t)b * 2048 * 3072 + h * 64;
  const ushort* Kp = Qp + 1024;
  const ushort* Vp = Qp + 2048;

  s16x8 qf0 = *(const s16x8*)(Qp + (size_t)(q0 + lrow) * 3072 + 8 * lg);
  s16x8 qf1 = *(const s16x8*)(Qp + (size_t)(q0 + lrow) * 3072 + 32 + 8 * lg);

  const f32x4 zero = {0.f, 0.f, 0.f, 0.f};
  f32x4 o[4];
  o[0] = zero; o[1] = zero; o[2] = zero; o[3] = zero;
  float mrun = -3e38f, lsum = 0.f;
  const int q_abs = q0 + lrow;
  const float SCL = 0.18033688011112042f;  // 1/8 * log2(e)

  const int sp = tid >> 3;
  const int sg = tid & 7;
  const int kr0 = tid >> 3;
  const int kc = tid & 7;
  const int vx = (lrow & 7) ^ (lrow >> 3);

  for (int kv = kv_lo; kv < kv_hi; kv += 64) {
    const bool needMask = !isGlobal && (kv < q0b - 64 || kv + 64 > q0b + 128);

    const ushort* vrow = Vp + (size_t)(kv + 2 * sp) * 3072 + 8 * sg;
    s16x8 vlo = *(const s16x8*)vrow;
    s16x8 vhi = *(const s16x8*)(vrow + 3072);

    __syncthreads();

    GLDS(Kp + (size_t)(kv + kr0) * 3072 + 8 * (kc ^ (kr0 & 7)), &Ks[w * 512]);
    GLDS(Kp + (size_t)(kv + 32 + kr0) * 3072 + 8 * (kc ^ (kr0 & 7)), &Ks[2048 + w * 512]);

#pragma unroll
    for (int j = 0; j < 8; j++) {
      const int d = 8 * sg + j;
      const int r = 2 * sp;
      uint pk = (uint)(ushort)vlo[j] | ((uint)(ushort)vhi[j] << 16);
      *(uint*)&Vt[d * 64 + ((((r >> 3) ^ j ^ sg) & 7) << 3) + (r & 7)] = pk;
    }
    __syncthreads();

#pragma unroll
    for (int s = 0; s < 2; s++) {
      const int kb = kv + 32 * s;
      const int rs = 32 * s;
      s16x8 kA0 = *(const s16x8*)&Ks[(rs + lrow) * 64      + ((( lg      ^ (lrow & 7)) & 7) << 3)];
      s16x8 kA1 = *(const s16x8*)&Ks[(rs + lrow) * 64      + ((((4 + lg) ^ (lrow & 7)) & 7) << 3)];
      s16x8 kB0 = *(const s16x8*)&Ks[(rs + 16 + lrow) * 64 + ((( lg      ^ (lrow & 7)) & 7) << 3)];
      s16x8 kB1 = *(const s16x8*)&Ks[(rs + 16 + lrow) * 64 + ((((4 + lg) ^ (lrow & 7)) & 7) << 3)];

      f32x4 sA = __builtin_amdgcn_mfma_f32_16x16x32_bf16(kA0, qf0, zero, 0, 0, 0);
      sA = __builtin_amdgcn_mfma_f32_16x16x32_bf16(kA1, qf1, sA, 0, 0, 0);
      f32x4 sB = __builtin_amdgcn_mfma_f32_16x16x32_bf16(kB0, qf0, zero, 0, 0, 0);
      sB = __builtin_amdgcn_mfma_f32_16x16x32_bf16(kB1, qf1, sB, 0, 0, 0);

      float pA[4], pB[4];
      float rowmax = -3e38f;
      if (needMask) {
#pragma unroll
        for (int i = 0; i < 4; i++) {
          int kaA = kb + 4 * lg + i;
          int dq = q_abs - kaA;
          float va = (dq <= 128 && dq >= -128) ? sA[i] * SCL : -1e30f;
          pA[i] = va; rowmax = fmaxf(rowmax, va);
          int dqb = dq - 16;
          float vb = (dqb <= 128 && dqb >= -128) ? sB[i] * SCL : -1e30f;
          pB[i] = vb; rowmax = fmaxf(rowmax, vb);
        }
      } else {
#pragma unroll
        for (int i = 0; i < 4; i++) {
          pA[i] = sA[i] * SCL; pB[i] = sB[i] * SCL;
          rowmax = fmaxf(rowmax, fmaxf(pA[i], pB[i]));
        }
      }
      rowmax = fmaxf(rowmax, __shfl_xor(rowmax, 16));
      rowmax = fmaxf(rowmax, __shfl_xor(rowmax, 32));

      if (!__all(rowmax <= mrun + 8.f)) {
        float mnew = fmaxf(mrun, rowmax);
        float alpha = exp2f(mrun - mnew);
        mrun = mnew;
        lsum *= alpha;
        float a0 = __shfl(alpha, 4 * lg + 0);
        float a1 = __shfl(alpha, 4 * lg + 1);
        float a2 = __shfl(alpha, 4 * lg + 2);
        float a3 = __shfl(alpha, 4 * lg + 3);
#pragma unroll
        for (int c = 0; c < 4; c++) {
          o[c][0] *= a0; o[c][1] *= a1; o[c][2] *= a2; o[c][3] *= a3;
        }
      }

      float rsum = 0.f;
      if (needMask) {
#pragma unroll
        for (int i = 0; i < 4; i++) {
          pA[i] = (pA[i] > -1e29f) ? exp2f(pA[i] - mrun) : 0.f;
          pB[i] = (pB[i] > -1e29f) ? exp2f(pB[i] - mrun) : 0.f;
          rsum += pA[i] + pB[i];
        }
      } else {
#pragma unroll
        for (int i = 0; i < 4; i++) {
          pA[i] = exp2f(pA[i] - mrun);
          pB[i] = exp2f(pB[i] - mrun);
          rsum += pA[i] + pB[i];
        }
      }
      rsum += __shfl_xor(rsum, 16);
      rsum += __shfl_xor(rsum, 32);
      lsum += rsum;

      {
        ushort* P = &Ps[w][lrow * 40];
        *(uint*)&P[4 * lg]      = (uint)f2bf(pA[0]) | ((uint)f2bf(pA[1]) << 16);
        *(uint*)&P[4 * lg + 2]  = (uint)f2bf(pA[2]) | ((uint)f2bf(pA[3]) << 16);
        *(uint*)&P[16 + 4 * lg] = (uint)f2bf(pB[0]) | ((uint)f2bf(pB[1]) << 16);
        *(uint*)&P[18 + 4 * lg] = (uint)f2bf(pB[2]) | ((uint)f2bf(pB[3]) << 16);
      }
      s16x8 paf = *(const s16x8*)&Ps[w][lrow * 40 + 8 * lg];

#pragma unroll
      for (int c = 0; c < 4; c++) {
        const int d = 16 * c + lrow;
        s16x8 vf = *(const s16x8*)&Vt[d * 64 + ((((4 * s + lg) ^ vx ^ (2 * c)) & 7) << 3)];
        o[c] = __builtin_amdgcn_mfma_f32_16x16x32_bf16(paf, vf, o[c], 0, 0, 0);
      }
    }
  }

  if (isGlobal) {
    const size_t rbase = (size_t)(chunk * 4 + b) * 2048 + q0;
    if (lg == 0) {
      mPart[rbase + lrow] = mrun;
      lPart[rbase + lrow] = lsum;
    }
#pragma unroll
    for (int c = 0; c < 4; c++)
#pragma unroll
      for (int i = 0; i < 4; i++)
        oPart[(rbase + 4 * lg + i) * 64 + 16 * c + lrow] = o[c][i];
  } else {
    float li0 = 1.f / __shfl(lsum, 4 * lg + 0);
    float li1 = 1.f / __shfl(lsum, 4 * lg + 1);
    float li2 = 1.f / __shfl(lsum, 4 * lg + 2);
    float li3 = 1.f / __shfl(lsum, 4 * lg + 3);
    size_t orow = (size_t)(b * 2048 + q0 + 4 * lg);
#pragma unroll
    for (int c = 0; c < 4; c++) {
      outp[(orow + 0) * 1024 + h * 64 + 16 * c + lrow] = f2bf(o[c][0] * li0);
      outp[(orow + 1) * 1024 + h * 64 + 16 * c + lrow] = f2bf(o[c][1] * li1);
      outp[(orow + 2) * 1024 + h * 64 + 16 * c + lrow] = f2bf(o[c][2] * li2);
      outp[(orow + 3) * 1024 + h * 64 + 16 * c + lrow] = f2bf(o[c][3] * li3);
    }
  }
}

// ---------------- combine global-head partials ----------------
__global__ __launch_bounds__(256) void combine_kernel(const float* __restrict__ oPart,
                                                      const float* __restrict__ mPart,
                                                      const float* __restrict__ lPart,
                                                      ushort* __restrict__ attno) {
  const int tid = threadIdx.x;
  const int row = blockIdx.x * 64 + (tid >> 2);   // 0..8191
  const int d0 = (tid & 3) * 16;
  float m[8], l[8], M = -3e38f;
#pragma unroll
  for (int p = 0; p < 8; p++) {
    m[p] = mPart[p * 8192 + row];
    l[p] = lPart[p * 8192 + row];
    M = fmaxf(M, m[p]);
  }
  float L = 0.f, wgt[8];
#pragma unroll
  for (int p = 0; p < 8; p++) { wgt[p] = exp2f(m[p] - M); L += wgt[p] * l[p]; }
  float inv = 1.f / L;
  float acc[16];
#pragma unroll
  for (int j = 0; j < 16; j++) acc[j] = 0.f;
#pragma unroll
  for (int p = 0; p < 8; p++) {
    const float* op = oPart + ((size_t)p * 8192 + row) * 64 + d0;
    float wv = wgt[p];
#pragma unroll
    for (int j = 0; j < 16; j += 4) {
      float4 v = *(const float4*)(op + j);
      acc[j]     += wv * v.x; acc[j + 1] += wv * v.y;
      acc[j + 2] += wv * v.z; acc[j + 3] += wv * v.w;
    }
  }
  ushort* dst = attno + (size_t)row * 1024 + d0;
#pragma unroll
  for (int j = 0; j < 16; j++) dst[j] = f2bf(acc[j] * inv);
}

// ---------------- launch ----------------
extern "C" void kernel_launch(void* const* d_in, const int* in_sizes, int n_in,
                              void* d_out, int out_size, void* d_ws, size_t ws_size,
                              hipStream_t stream) {
  const float* x  = (const float*)d_in[0];
  const float* wq = (const float*)d_in[1];
  const float* bq = (const float*)d_in[2];
  const float* wk = (const float*)d_in[3];
  const float* bk = (const float*)d_in[4];
  const float* wv = (const float*)d_in[5];
  const float* bv = (const float*)d_in[6];
  const float* wo = (const float*)d_in[7];
  const float* bo = (const float*)d_in[8];

  char* ws = (char*)d_ws;
  ushort* xb    = (ushort*)(ws);                 // 8192x1024 bf16 = 16 MB
  ushort* wqkvb = (ushort*)(ws + 16777216);      // 3072x1024 bf16 =  6 MB
  ushort* wob   = (ushort*)(ws + 23068672);      // 1024x1024 bf16 =  2 MB
  ushort* qkvb  = (ushort*)(ws + 25165824);      // 8192x3072 bf16 = 48 MB
  ushort* attno = (ushort*)(ws + 75497472);      // 8192x1024 bf16 = 16 MB
  // partials overwrite xb/wqkvb region (dead after gemm1)
  float* oPart = (float*)(ws);                   // 8x8192x64 f32 = 16 MB
  float* mPart = (float*)(ws + 16777216);        // 8x8192 f32 = 256 KB
  float* lPart = (float*)(ws + 16777216 + 262144);

  castk<<<8192, 256, 0, stream>>>(x, xb, 8388608);
  castw<<<4096, 256, 0, stream>>>(wq, wk, wv, wo,
                                  wqkvb, wqkvb + 1048576, wqkvb + 2097152, wob);

  gemm_bt<<<dim3(24, 64), 256, 0, stream>>>(xb, wqkvb, bq, bk, bv,
                                            (void*)qkvb, 8192, 3072, 1024, 1);

  attn_kernel<<<2944, 256, 0, stream>>>(qkvb, attno, oPart, mPart, lPart);
  combine_kernel<<<128, 256, 0, stream>>>(oPart, mPart, lPart, attno);

  gemm_bt<<<dim3(8, 64), 256, 0, stream>>>(attno, wob, bo, nullptr, nullptr,
                                           (void*)d_out, 8192, 1024, 1024, 0);
}

// Round 4
// 167.053 us; speedup vs baseline: 1.9420x; 1.0978x over previous
//
#include <hip/hip_runtime.h>

typedef __attribute__((ext_vector_type(4))) float f32x4;
typedef __attribute__((ext_vector_type(8))) short s16x8;

#define GLDS(gsrc, ldst) \
  __builtin_amdgcn_global_load_lds((const __attribute__((address_space(1))) void*)(gsrc), \
                                   (__attribute__((address_space(3))) void*)(ldst), 16, 0, 0)

__device__ __forceinline__ ushort f2bf(float f) {
  union { float f; unsigned u; } x; x.f = f;
  unsigned r = (x.u + 0x7FFFu + ((x.u >> 16) & 1u)) >> 16;
  return (ushort)r;
}

// ---------------- cast f32 -> bf16 (vectorized) ----------------
__global__ __launch_bounds__(256) void castk(const float* __restrict__ in,
                                             ushort* __restrict__ outp, int n) {
  int i = (blockIdx.x * 256 + threadIdx.x) * 4;
  if (i >= n) return;
  float4 v = *(const float4*)(in + i);
  ushort4 r;
  r.x = f2bf(v.x); r.y = f2bf(v.y); r.z = f2bf(v.z); r.w = f2bf(v.w);
  *(ushort4*)(outp + i) = r;
}

__global__ __launch_bounds__(256) void castw(const float* __restrict__ w0, const float* __restrict__ w1,
                                             const float* __restrict__ w2, const float* __restrict__ w3,
                                             ushort* __restrict__ o0, ushort* __restrict__ o1,
                                             ushort* __restrict__ o2, ushort* __restrict__ o3) {
  int bid = blockIdx.x;
  int sel = bid >> 10;
  const float* in = (sel == 0) ? w0 : (sel == 1) ? w1 : (sel == 2) ? w2 : w3;
  ushort* outp    = (sel == 0) ? o0 : (sel == 1) ? o1 : (sel == 2) ? o2 : o3;
  int i = ((bid & 1023) * 256 + threadIdx.x) * 4;
  float4 v = *(const float4*)(in + i);
  ushort4 r;
  r.x = f2bf(v.x); r.y = f2bf(v.y); r.z = f2bf(v.z); r.w = f2bf(v.w);
  *(ushort4*)(outp + i) = r;
}

// ---------------- GEMM 128x256, BK=64, 8 waves, triple-buffered ----------------
// C[M,N] = A[M,K] * Bt[N,K]^T + bias.  K multiple of 64, NT = K/64 >= 2.
// LDS per buffer: A[128][64] (8192 us) + B[256][64] (16384 us) = 24576 ushorts; x3 = 144KB.
// Swizzle: 16B granule g of row r stored at granule (g ^ (r&7)) [involution].
template<int OUTBF16>
__global__ __launch_bounds__(512, 2) void gemm256(
    const ushort* __restrict__ A, const ushort* __restrict__ Bt,
    const float* __restrict__ bias0, const float* __restrict__ bias1,
    const float* __restrict__ bias2,
    void* __restrict__ Cout, int M, int N, int K, int nxn)
{
  __shared__ __align__(16) ushort lds[73728];
  const int tid = threadIdx.x;
  const int w = tid >> 6, lane = tid & 63;
  const int lrow = lane & 15, lg = lane >> 4;
  const int wm = w >> 2, wn = w & 3;          // 2M x 4N wave grid, per-wave 64x64
  // chunked bijective XCD swizzle (gridDim.x divisible by 8)
  const int cpx = gridDim.x >> 3;
  const int wgid = ((int)blockIdx.x & 7) * cpx + ((int)blockIdx.x >> 3);
  const int mblk = (wgid / nxn) * 128;
  const int nblk = (wgid % nxn) * 256;
  const int NT = K >> 6;

  // staging coords: thread covers row (r*64 + srow), 16B granule (tid&7)^ (srow&7)
  const int srow = tid >> 3;
  const int scol = 8 * ((tid & 7) ^ (srow & 7));
  const ushort* Abase = A + (size_t)(mblk + srow) * K + scol;
  const ushort* Bbase = Bt + (size_t)(nblk + srow) * K + scol;
  const size_t rstep = (size_t)64 * K;
  const int dA = w * 512;            // + r*4096 + buf*24576   (ushort idx)
  const int dB = 8192 + w * 512;

#define STAGE_A(kt, bf) { \
    GLDS(Abase + (size_t)(kt) * 64,         &lds[(bf) * 24576 + dA]); \
    GLDS(Abase + (size_t)(kt) * 64 + rstep, &lds[(bf) * 24576 + dA + 4096]); }
#define STAGE_B(kt, bf) { \
    GLDS(Bbase + (size_t)(kt) * 64,             &lds[(bf) * 24576 + dB]); \
    GLDS(Bbase + (size_t)(kt) * 64 + rstep,     &lds[(bf) * 24576 + dB + 4096]); \
    GLDS(Bbase + (size_t)(kt) * 64 + 2 * rstep, &lds[(bf) * 24576 + dB + 8192]); \
    GLDS(Bbase + (size_t)(kt) * 64 + 3 * rstep, &lds[(bf) * 24576 + dB + 12288]); }

  // fragment read offsets (ushort idx, within buffer)
  int offA[4][2], offB[4][2];
#pragma unroll
  for (int m = 0; m < 4; m++)
#pragma unroll
    for (int kk = 0; kk < 2; kk++) {
      offA[m][kk] = (wm * 64 + m * 16 + lrow) * 64 + (((kk * 4 + lg) ^ (lrow & 7)) << 3);
      offB[m][kk] = 8192 + (wn * 64 + m * 16 + lrow) * 64 + (((kk * 4 + lg) ^ (lrow & 7)) << 3);
    }

  const f32x4 zero = {0.f, 0.f, 0.f, 0.f};
  f32x4 acc[4][4];
#pragma unroll
  for (int m = 0; m < 4; m++)
#pragma unroll
    for (int n = 0; n < 4; n++) acc[m][n] = zero;

  // prologue: stage tiles 0 and 1
  STAGE_A(0, 0); STAGE_B(0, 0);
  if (NT > 1) { STAGE_A(1, 1); STAGE_B(1, 1); }

  int b = 0;
  for (int t = 0; t < NT; ++t) {
    if (t < NT - 1) { asm volatile("s_waitcnt vmcnt(6)" ::: "memory"); }
    else            { asm volatile("s_waitcnt vmcnt(0)" ::: "memory"); }
    __builtin_amdgcn_s_barrier();
    const int bb = b * 24576;
    const int t2 = t + 2;
    const int b2 = (b >= 1) ? b - 1 : 2;   // (b+2)%3

    // phase 0: kk = 0
    if (t2 < NT) STAGE_A(t2, b2);
    {
      s16x8 af[4], bf_[4];
#pragma unroll
      for (int m = 0; m < 4; m++) af[m] = *(const s16x8*)&lds[bb + offA[m][0]];
#pragma unroll
      for (int n = 0; n < 4; n++) bf_[n] = *(const s16x8*)&lds[bb + offB[n][0]];
      __builtin_amdgcn_s_setprio(1);
#pragma unroll
      for (int m = 0; m < 4; m++)
#pragma unroll
        for (int n = 0; n < 4; n++)
          acc[m][n] = __builtin_amdgcn_mfma_f32_16x16x32_bf16(af[m], bf_[n], acc[m][n], 0, 0, 0);
      __builtin_amdgcn_s_setprio(0);
    }
    // phase 1: kk = 1
    if (t2 < NT) STAGE_B(t2, b2);
    {
      s16x8 af[4], bf_[4];
#pragma unroll
      for (int m = 0; m < 4; m++) af[m] = *(const s16x8*)&lds[bb + offA[m][1]];
#pragma unroll
      for (int n = 0; n < 4; n++) bf_[n] = *(const s16x8*)&lds[bb + offB[n][1]];
      __builtin_amdgcn_s_setprio(1);
#pragma unroll
      for (int m = 0; m < 4; m++)
#pragma unroll
        for (int n = 0; n < 4; n++)
          acc[m][n] = __builtin_amdgcn_mfma_f32_16x16x32_bf16(af[m], bf_[n], acc[m][n], 0, 0, 0);
      __builtin_amdgcn_s_setprio(0);
    }
    b = (b == 2) ? 0 : b + 1;
  }
#undef STAGE_A
#undef STAGE_B

  // bias per n-fragment column
  float bias_n[4];
#pragma unroll
  for (int n = 0; n < 4; n++) {
    const int col = nblk + wn * 64 + n * 16 + lrow;
    if (bias1) bias_n[n] = (col < 1024) ? bias0[col]
                          : (col < 2048 ? bias1[col - 1024] : bias2[col - 2048]);
    else bias_n[n] = bias0[col];
  }

  __syncthreads();   // all LDS tile reads done; reuse LDS as C staging

  if (OUTBF16) {
    ushort* Ct = lds;
#pragma unroll
    for (int m = 0; m < 4; m++)
#pragma unroll
      for (int n = 0; n < 4; n++)
#pragma unroll
        for (int i = 0; i < 4; i++)
          Ct[(wm * 64 + m * 16 + 4 * lg + i) * 256 + wn * 64 + n * 16 + lrow] =
              f2bf(acc[m][n][i] + bias_n[n]);
    __syncthreads();
    ushort* Cg = (ushort*)Cout;
#pragma unroll
    for (int r = 0; r < 8; r++) {
      const int row = r * 16 + (tid >> 5);
      const int col = (tid & 31) * 8;
      *(s16x8*)&Cg[(size_t)(mblk + row) * N + nblk + col] = *(const s16x8*)&lds[r * 4096 + tid * 8];
    }
  } else {
    float* Cf = (float*)lds;
#pragma unroll
    for (int m = 0; m < 4; m++)
#pragma unroll
      for (int n = 0; n < 4; n++)
#pragma unroll
        for (int i = 0; i < 4; i++)
          Cf[(wm * 64 + m * 16 + 4 * lg + i) * 256 + wn * 64 + n * 16 + lrow] =
              acc[m][n][i] + bias_n[n];
    __syncthreads();
    float* Cg = (float*)Cout;
#pragma unroll
    for (int r = 0; r < 16; r++) {
      const int row = r * 8 + (tid >> 6);
      const int col = (tid & 63) * 4;
      *(float4*)&Cg[(size_t)(mblk + row) * N + nblk + col] = *(const float4*)&Cf[r * 2048 + tid * 4];
    }
  }
}

// ---------------- banded / global flash attention (balanced) ----------------
__global__ __launch_bounds__(256) void attn_kernel(const ushort* __restrict__ qkv,
                                                   ushort* __restrict__ outp,
                                                   float* __restrict__ oPart,
                                                   float* __restrict__ mPart,
                                                   float* __restrict__ lPart)
{
  __shared__ __align__(16) ushort Ks[64 * 64];
  __shared__ __align__(16) ushort Vt[64 * 64];
  __shared__ __align__(16) ushort Ps[4][16 * 40];

  const int tid = threadIdx.x;
  const int w = tid >> 6, lane = tid & 63;
  const int lrow = lane & 15, lg = lane >> 4;

  const int bid = (blockIdx.x & 7) * 368 + (blockIdx.x >> 3);
  int h, b, bx, kv_lo, kv_hi, chunk = 0;
  bool isGlobal;
  if (bid < 1024) {
    isGlobal = true; h = 0;
    chunk = bid >> 7;
    int qb = bid & 127;
    b = qb >> 5; bx = qb & 31;
    kv_lo = chunk * 256; kv_hi = kv_lo + 256;
  } else {
    isGlobal = false;
    int t = bid - 1024;
    h = 1 + (t >> 7);
    int qb = t & 127;
    b = qb >> 5; bx = qb & 31;
    kv_lo = bx * 64 - 128; if (kv_lo < 0) kv_lo = 0;
    kv_hi = bx * 64 + 192; if (kv_hi > 2048) kv_hi = 2048;
  }
  const int q0b = bx * 64;
  const int q0 = q0b + w * 16;
  const ushort* Qp = qkv + (size_t)b * 2048 * 3072 + h * 64;
  const ushort* Kp = Qp + 1024;
  const ushort* Vp = Qp + 2048;

  s16x8 qf0 = *(const s16x8*)(Qp + (size_t)(q0 + lrow) * 3072 + 8 * lg);
  s16x8 qf1 = *(const s16x8*)(Qp + (size_t)(q0 + lrow) * 3072 + 32 + 8 * lg);

  const f32x4 zero = {0.f, 0.f, 0.f, 0.f};
  f32x4 o[4];
  o[0] = zero; o[1] = zero; o[2] = zero; o[3] = zero;
  float mrun = -3e38f, lsum = 0.f;
  const int q_abs = q0 + lrow;
  const float SCL = 0.18033688011112042f;  // 1/8 * log2(e)

  const int sp = tid >> 3;
  const int sg = tid & 7;
  const int kr0 = tid >> 3;
  const int kc = tid & 7;
  const int vx = (lrow & 7) ^ (lrow >> 3);

  for (int kv = kv_lo; kv < kv_hi; kv += 64) {
    const bool needMask = !isGlobal && (kv < q0b - 64 || kv + 64 > q0b + 128);

    const ushort* vrow = Vp + (size_t)(kv + 2 * sp) * 3072 + 8 * sg;
    s16x8 vlo = *(const s16x8*)vrow;
    s16x8 vhi = *(const s16x8*)(vrow + 3072);

    __syncthreads();

    GLDS(Kp + (size_t)(kv + kr0) * 3072 + 8 * (kc ^ (kr0 & 7)), &Ks[w * 512]);
    GLDS(Kp + (size_t)(kv + 32 + kr0) * 3072 + 8 * (kc ^ (kr0 & 7)), &Ks[2048 + w * 512]);

#pragma unroll
    for (int j = 0; j < 8; j++) {
      const int d = 8 * sg + j;
      const int r = 2 * sp;
      uint pk = (uint)(ushort)vlo[j] | ((uint)(ushort)vhi[j] << 16);
      *(uint*)&Vt[d * 64 + ((((r >> 3) ^ j ^ sg) & 7) << 3) + (r & 7)] = pk;
    }
    __syncthreads();

#pragma unroll
    for (int s = 0; s < 2; s++) {
      const int kb = kv + 32 * s;
      const int rs = 32 * s;
      s16x8 kA0 = *(const s16x8*)&Ks[(rs + lrow) * 64      + ((( lg      ^ (lrow & 7)) & 7) << 3)];
      s16x8 kA1 = *(const s16x8*)&Ks[(rs + lrow) * 64      + ((((4 + lg) ^ (lrow & 7)) & 7) << 3)];
      s16x8 kB0 = *(const s16x8*)&Ks[(rs + 16 + lrow) * 64 + ((( lg      ^ (lrow & 7)) & 7) << 3)];
      s16x8 kB1 = *(const s16x8*)&Ks[(rs + 16 + lrow) * 64 + ((((4 + lg) ^ (lrow & 7)) & 7) << 3)];

      f32x4 sA = __builtin_amdgcn_mfma_f32_16x16x32_bf16(kA0, qf0, zero, 0, 0, 0);
      sA = __builtin_amdgcn_mfma_f32_16x16x32_bf16(kA1, qf1, sA, 0, 0, 0);
      f32x4 sB = __builtin_amdgcn_mfma_f32_16x16x32_bf16(kB0, qf0, zero, 0, 0, 0);
      sB = __builtin_amdgcn_mfma_f32_16x16x32_bf16(kB1, qf1, sB, 0, 0, 0);

      float pA[4], pB[4];
      float rowmax = -3e38f;
      if (needMask) {
#pragma unroll
        for (int i = 0; i < 4; i++) {
          int kaA = kb + 4 * lg + i;
          int dq = q_abs - kaA;
          float va = (dq <= 128 && dq >= -128) ? sA[i] * SCL : -1e30f;
          pA[i] = va; rowmax = fmaxf(rowmax, va);
          int dqb = dq - 16;
          float vb = (dqb <= 128 && dqb >= -128) ? sB[i] * SCL : -1e30f;
          pB[i] = vb; rowmax = fmaxf(rowmax, vb);
        }
      } else {
#pragma unroll
        for (int i = 0; i < 4; i++) {
          pA[i] = sA[i] * SCL; pB[i] = sB[i] * SCL;
          rowmax = fmaxf(rowmax, fmaxf(pA[i], pB[i]));
        }
      }
      rowmax = fmaxf(rowmax, __shfl_xor(rowmax, 16));
      rowmax = fmaxf(rowmax, __shfl_xor(rowmax, 32));

      if (!__all(rowmax <= mrun + 8.f)) {
        float mnew = fmaxf(mrun, rowmax);
        float alpha = exp2f(mrun - mnew);
        mrun = mnew;
        lsum *= alpha;
        float a0 = __shfl(alpha, 4 * lg + 0);
        float a1 = __shfl(alpha, 4 * lg + 1);
        float a2 = __shfl(alpha, 4 * lg + 2);
        float a3 = __shfl(alpha, 4 * lg + 3);
#pragma unroll
        for (int c = 0; c < 4; c++) {
          o[c][0] *= a0; o[c][1] *= a1; o[c][2] *= a2; o[c][3] *= a3;
        }
      }

      float rsum = 0.f;
      if (needMask) {
#pragma unroll
        for (int i = 0; i < 4; i++) {
          pA[i] = (pA[i] > -1e29f) ? exp2f(pA[i] - mrun) : 0.f;
          pB[i] = (pB[i] > -1e29f) ? exp2f(pB[i] - mrun) : 0.f;
          rsum += pA[i] + pB[i];
        }
      } else {
#pragma unroll
        for (int i = 0; i < 4; i++) {
          pA[i] = exp2f(pA[i] - mrun);
          pB[i] = exp2f(pB[i] - mrun);
          rsum += pA[i] + pB[i];
        }
      }
      rsum += __shfl_xor(rsum, 16);
      rsum += __shfl_xor(rsum, 32);
      lsum += rsum;

      {
        ushort* P = &Ps[w][lrow * 40];
        *(uint*)&P[4 * lg]      = (uint)f2bf(pA[0]) | ((uint)f2bf(pA[1]) << 16);
        *(uint*)&P[4 * lg + 2]  = (uint)f2bf(pA[2]) | ((uint)f2bf(pA[3]) << 16);
        *(uint*)&P[16 + 4 * lg] = (uint)f2bf(pB[0]) | ((uint)f2bf(pB[1]) << 16);
        *(uint*)&P[18 + 4 * lg] = (uint)f2bf(pB[2]) | ((uint)f2bf(pB[3]) << 16);
      }
      s16x8 paf = *(const s16x8*)&Ps[w][lrow * 40 + 8 * lg];

#pragma unroll
      for (int c = 0; c < 4; c++) {
        const int d = 16 * c + lrow;
        s16x8 vf = *(const s16x8*)&Vt[d * 64 + ((((4 * s + lg) ^ vx ^ (2 * c)) & 7) << 3)];
        o[c] = __builtin_amdgcn_mfma_f32_16x16x32_bf16(paf, vf, o[c], 0, 0, 0);
      }
    }
  }

  if (isGlobal) {
    const size_t rbase = (size_t)(chunk * 4 + b) * 2048 + q0;
    if (lg == 0) {
      mPart[rbase + lrow] = mrun;
      lPart[rbase + lrow] = lsum;
    }
#pragma unroll
    for (int c = 0; c < 4; c++)
#pragma unroll
      for (int i = 0; i < 4; i++)
        oPart[(rbase + 4 * lg + i) * 64 + 16 * c + lrow] = o[c][i];
  } else {
    float li0 = 1.f / __shfl(lsum, 4 * lg + 0);
    float li1 = 1.f / __shfl(lsum, 4 * lg + 1);
    float li2 = 1.f / __shfl(lsum, 4 * lg + 2);
    float li3 = 1.f / __shfl(lsum, 4 * lg + 3);
    size_t orow = (size_t)(b * 2048 + q0 + 4 * lg);
#pragma unroll
    for (int c = 0; c < 4; c++) {
      outp[(orow + 0) * 1024 + h * 64 + 16 * c + lrow] = f2bf(o[c][0] * li0);
      outp[(orow + 1) * 1024 + h * 64 + 16 * c + lrow] = f2bf(o[c][1] * li1);
      outp[(orow + 2) * 1024 + h * 64 + 16 * c + lrow] = f2bf(o[c][2] * li2);
      outp[(orow + 3) * 1024 + h * 64 + 16 * c + lrow] = f2bf(o[c][3] * li3);
    }
  }
}

// ---------------- combine global-head partials ----------------
__global__ __launch_bounds__(256) void combine_kernel(const float* __restrict__ oPart,
                                                      const float* __restrict__ mPart,
                                                      const float* __restrict__ lPart,
                                                      ushort* __restrict__ attno) {
  const int tid = threadIdx.x;
  const int row = blockIdx.x * 64 + (tid >> 2);
  const int d0 = (tid & 3) * 16;
  float m[8], l[8], M = -3e38f;
#pragma unroll
  for (int p = 0; p < 8; p++) {
    m[p] = mPart[p * 8192 + row];
    l[p] = lPart[p * 8192 + row];
    M = fmaxf(M, m[p]);
  }
  float L = 0.f, wgt[8];
#pragma unroll
  for (int p = 0; p < 8; p++) { wgt[p] = exp2f(m[p] - M); L += wgt[p] * l[p]; }
  float inv = 1.f / L;
  float acc[16];
#pragma unroll
  for (int j = 0; j < 16; j++) acc[j] = 0.f;
#pragma unroll
  for (int p = 0; p < 8; p++) {
    const float* op = oPart + ((size_t)p * 8192 + row) * 64 + d0;
    float wv = wgt[p];
#pragma unroll
    for (int j = 0; j < 16; j += 4) {
      float4 v = *(const float4*)(op + j);
      acc[j]     += wv * v.x; acc[j + 1] += wv * v.y;
      acc[j + 2] += wv * v.z; acc[j + 3] += wv * v.w;
    }
  }
  ushort* dst = attno + (size_t)row * 1024 + d0;
#pragma unroll
  for (int j = 0; j < 16; j++) dst[j] = f2bf(acc[j] * inv);
}

// ---------------- launch ----------------
extern "C" void kernel_launch(void* const* d_in, const int* in_sizes, int n_in,
                              void* d_out, int out_size, void* d_ws, size_t ws_size,
                              hipStream_t stream) {
  const float* x  = (const float*)d_in[0];
  const float* wq = (const float*)d_in[1];
  const float* bq = (const float*)d_in[2];
  const float* wk = (const float*)d_in[3];
  const float* bk = (const float*)d_in[4];
  const float* wv = (const float*)d_in[5];
  const float* bv = (const float*)d_in[6];
  const float* wo = (const float*)d_in[7];
  const float* bo = (const float*)d_in[8];

  char* ws = (char*)d_ws;
  ushort* xb    = (ushort*)(ws);                 // 8192x1024 bf16 = 16 MB
  ushort* wqkvb = (ushort*)(ws + 16777216);      // 3072x1024 bf16 =  6 MB
  ushort* wob   = (ushort*)(ws + 23068672);      // 1024x1024 bf16 =  2 MB
  ushort* qkvb  = (ushort*)(ws + 25165824);      // 8192x3072 bf16 = 48 MB
  ushort* attno = (ushort*)(ws + 75497472);      // 8192x1024 bf16 = 16 MB
  float* oPart = (float*)(ws);                   // 8x8192x64 f32 = 16 MB (over xb)
  float* mPart = (float*)(ws + 16777216);
  float* lPart = (float*)(ws + 16777216 + 262144);

  castk<<<8192, 256, 0, stream>>>(x, xb, 8388608);
  castw<<<4096, 256, 0, stream>>>(wq, wk, wv, wo,
                                  wqkvb, wqkvb + 1048576, wqkvb + 2097152, wob);

  // QKV projection: [8192,3072] = xb * wqkvb^T ; grid 64x12 = 768 blocks
  gemm256<1><<<768, 512, 0, stream>>>(xb, wqkvb, bq, bk, bv,
                                      (void*)qkvb, 8192, 3072, 1024, 12);

  attn_kernel<<<2944, 256, 0, stream>>>(qkvb, attno, oPart, mPart, lPart);
  combine_kernel<<<128, 256, 0, stream>>>(oPart, mPart, lPart, attno);

  // output projection: grid 64x4 = 256 blocks, f32 out
  gemm256<0><<<256, 512, 0, stream>>>(attno, wob, bo, nullptr, nullptr,
                                      (void*)d_out, 8192, 1024, 1024, 4);
}

// Round 5
// 165.578 us; speedup vs baseline: 1.9593x; 1.0089x over previous
//
#include <hip/hip_runtime.h>

typedef __attribute__((ext_vector_type(4))) float f32x4;
typedef __attribute__((ext_vector_type(8))) short s16x8;

#define GLDS(gsrc, ldst) \
  __builtin_amdgcn_global_load_lds((const __attribute__((address_space(1))) void*)(gsrc), \
                                   (__attribute__((address_space(3))) void*)(ldst), 16, 0, 0)

__device__ __forceinline__ ushort f2bf(float f) {
  union { float f; unsigned u; } x; x.f = f;
  unsigned r = (x.u + 0x7FFFu + ((x.u >> 16) & 1u)) >> 16;
  return (ushort)r;
}

// ---------------- cast f32 -> bf16 (vectorized) ----------------
__global__ __launch_bounds__(256) void castk(const float* __restrict__ in,
                                             ushort* __restrict__ outp, int n) {
  int i = (blockIdx.x * 256 + threadIdx.x) * 4;
  if (i >= n) return;
  float4 v = *(const float4*)(in + i);
  ushort4 r;
  r.x = f2bf(v.x); r.y = f2bf(v.y); r.z = f2bf(v.z); r.w = f2bf(v.w);
  *(ushort4*)(outp + i) = r;
}

__global__ __launch_bounds__(256) void castw(const float* __restrict__ w0, const float* __restrict__ w1,
                                             const float* __restrict__ w2, const float* __restrict__ w3,
                                             ushort* __restrict__ o0, ushort* __restrict__ o1,
                                             ushort* __restrict__ o2, ushort* __restrict__ o3) {
  int bid = blockIdx.x;
  int sel = bid >> 10;
  const float* in = (sel == 0) ? w0 : (sel == 1) ? w1 : (sel == 2) ? w2 : w3;
  ushort* outp    = (sel == 0) ? o0 : (sel == 1) ? o1 : (sel == 2) ? o2 : o3;
  int i = ((bid & 1023) * 256 + threadIdx.x) * 4;
  float4 v = *(const float4*)(in + i);
  ushort4 r;
  r.x = f2bf(v.x); r.y = f2bf(v.y); r.z = f2bf(v.z); r.w = f2bf(v.w);
  *(ushort4*)(outp + i) = r;
}

// ---------------- GEMM 128x256, BK=64, 8 waves, triple-buffered ----------------
// C[M,N] = A[M,K] * Bt[N,K]^T + bias.  K multiple of 64, NT = K/64 >= 2.
// LDS per buffer: A[128][64] + B[256][64] = 24576 ushorts; x3 = 144KB.
// Swizzle: 16B granule g of row r stored at granule (g ^ (r&7)) [involution].
// ds_read addressing: runtime base per (buffer,kk) + compile-time offset m*2048B.
template<int OUTBF16>
__global__ __launch_bounds__(512, 2) void gemm256(
    const ushort* __restrict__ A, const ushort* __restrict__ Bt,
    const float* __restrict__ bias0, const float* __restrict__ bias1,
    const float* __restrict__ bias2,
    void* __restrict__ Cout, int M, int N, int K, int nxn)
{
  __shared__ __align__(16) ushort lds[73728];
  const int tid = threadIdx.x;
  const int w = tid >> 6, lane = tid & 63;
  const int lrow = lane & 15, lg = lane >> 4;
  const int wm = w >> 2, wn = w & 3;          // 2M x 4N wave grid, per-wave 64x64
  const int cpx = gridDim.x >> 3;
  const int wgid = ((int)blockIdx.x & 7) * cpx + ((int)blockIdx.x >> 3);
  const int mblk = (wgid / nxn) * 128;
  const int nblk = (wgid % nxn) * 256;
  const int NT = K >> 6;

  // staging coords: thread covers row (r*64 + srow), 16B granule (tid&7)^(srow&7)
  const int srow = tid >> 3;
  const int scol = 8 * ((tid & 7) ^ (srow & 7));
  const ushort* Abase = A + (size_t)(mblk + srow) * K + scol;
  const ushort* Bbase = Bt + (size_t)(nblk + srow) * K + scol;
  const size_t rstep = (size_t)64 * K;
  const int dA = w * 512;            // ushort idx within buffer
  const int dB = 8192 + w * 512;

#define STAGE_A(p, bf) { \
    GLDS((p),         &lds[(bf) + dA]); \
    GLDS((p) + rstep, &lds[(bf) + dA + 4096]); }
#define STAGE_B(p, bf) { \
    GLDS((p),             &lds[(bf) + dB]); \
    GLDS((p) + rstep,     &lds[(bf) + dB + 4096]); \
    GLDS((p) + 2 * rstep, &lds[(bf) + dB + 8192]); \
    GLDS((p) + 3 * rstep, &lds[(bf) + dB + 12288]); }

  // lane-dependent ds-read bases (ushort idx, within buffer)
  const int laneA0 = (wm * 64 + lrow) * 64 + ((lg ^ (lrow & 7)) << 3);
  const int laneA1 = (wm * 64 + lrow) * 64 + (((4 + lg) ^ (lrow & 7)) << 3);
  const int laneB0 = 8192 + (wn * 64 + lrow) * 64 + ((lg ^ (lrow & 7)) << 3);
  const int laneB1 = 8192 + (wn * 64 + lrow) * 64 + (((4 + lg) ^ (lrow & 7)) << 3);

  const f32x4 zero = {0.f, 0.f, 0.f, 0.f};
  f32x4 acc[4][4];
#pragma unroll
  for (int m = 0; m < 4; m++)
#pragma unroll
    for (int n = 0; n < 4; n++) acc[m][n] = zero;

  // prologue: stage tiles 0 (buf 0) and 1 (buf 1)
  STAGE_A(Abase, 0); STAGE_B(Bbase, 0);
  if (NT > 1) { STAGE_A(Abase + 64, 24576); STAGE_B(Bbase + 64, 24576); }

  const ushort* aP = Abase + 128;   // next global k-offset to stage (tile 2)
  const ushort* bP = Bbase + 128;
  int bb = 0, bbS = 49152;          // read-buffer base, stage-buffer base ((b+2)%3)

  for (int t = 0; t < NT; ++t) {
    if (t < NT - 1) { asm volatile("s_waitcnt vmcnt(6)" ::: "memory"); }
    else            { asm volatile("s_waitcnt vmcnt(0)" ::: "memory"); }
    __builtin_amdgcn_s_barrier();
    const int pA0 = bb + laneA0, pA1 = bb + laneA1;
    const int pB0 = bb + laneB0, pB1 = bb + laneB1;
    const bool pf = (t + 2 < NT);

    // phase 0: kk = 0
    if (pf) STAGE_A(aP, bbS);
    {
      s16x8 af[4], bf_[4];
#pragma unroll
      for (int m = 0; m < 4; m++) af[m] = *(const s16x8*)&lds[pA0 + m * 1024];
#pragma unroll
      for (int n = 0; n < 4; n++) bf_[n] = *(const s16x8*)&lds[pB0 + n * 1024];
      __builtin_amdgcn_s_setprio(1);
#pragma unroll
      for (int m = 0; m < 4; m++)
#pragma unroll
        for (int n = 0; n < 4; n++)
          acc[m][n] = __builtin_amdgcn_mfma_f32_16x16x32_bf16(af[m], bf_[n], acc[m][n], 0, 0, 0);
      __builtin_amdgcn_s_setprio(0);
    }
    // phase 1: kk = 1
    if (pf) STAGE_B(bP, bbS);
    {
      s16x8 af[4], bf_[4];
#pragma unroll
      for (int m = 0; m < 4; m++) af[m] = *(const s16x8*)&lds[pA1 + m * 1024];
#pragma unroll
      for (int n = 0; n < 4; n++) bf_[n] = *(const s16x8*)&lds[pB1 + n * 1024];
      __builtin_amdgcn_s_setprio(1);
#pragma unroll
      for (int m = 0; m < 4; m++)
#pragma unroll
        for (int n = 0; n < 4; n++)
          acc[m][n] = __builtin_amdgcn_mfma_f32_16x16x32_bf16(af[m], bf_[n], acc[m][n], 0, 0, 0);
      __builtin_amdgcn_s_setprio(0);
    }
    if (pf) { aP += 64; bP += 64; }
    bb  = (bb  == 49152) ? 0 : bb + 24576;
    bbS = (bbS == 49152) ? 0 : bbS + 24576;
  }
#undef STAGE_A
#undef STAGE_B

  // bias per n-fragment column
  float bias_n[4];
#pragma unroll
  for (int n = 0; n < 4; n++) {
    const int col = nblk + wn * 64 + n * 16 + lrow;
    if (bias1) bias_n[n] = (col < 1024) ? bias0[col]
                          : (col < 2048 ? bias1[col - 1024] : bias2[col - 2048]);
    else bias_n[n] = bias0[col];
  }

  __syncthreads();   // all LDS tile reads done; reuse LDS as C staging

  if (OUTBF16) {
    ushort* Ct = lds;
#pragma unroll
    for (int m = 0; m < 4; m++)
#pragma unroll
      for (int n = 0; n < 4; n++)
#pragma unroll
        for (int i = 0; i < 4; i++)
          Ct[(wm * 64 + m * 16 + 4 * lg + i) * 256 + wn * 64 + n * 16 + lrow] =
              f2bf(acc[m][n][i] + bias_n[n]);
    __syncthreads();
    ushort* Cg = (ushort*)Cout;
#pragma unroll
    for (int r = 0; r < 8; r++) {
      const int row = r * 16 + (tid >> 5);
      const int col = (tid & 31) * 8;
      *(s16x8*)&Cg[(size_t)(mblk + row) * N + nblk + col] = *(const s16x8*)&lds[r * 4096 + tid * 8];
    }
  } else {
    float* Cf = (float*)lds;
#pragma unroll
    for (int m = 0; m < 4; m++)
#pragma unroll
      for (int n = 0; n < 4; n++)
#pragma unroll
        for (int i = 0; i < 4; i++)
          Cf[(wm * 64 + m * 16 + 4 * lg + i) * 256 + wn * 64 + n * 16 + lrow] =
              acc[m][n][i] + bias_n[n];
    __syncthreads();
    float* Cg = (float*)Cout;
#pragma unroll
    for (int r = 0; r < 16; r++) {
      const int row = r * 8 + (tid >> 6);
      const int col = (tid & 63) * 4;
      *(float4*)&Cg[(size_t)(mblk + row) * N + nblk + col] = *(const float4*)&Cf[r * 2048 + tid * 4];
    }
  }
}

// ---------------- banded / global flash attention (balanced) ----------------
__global__ __launch_bounds__(256) void attn_kernel(const ushort* __restrict__ qkv,
                                                   ushort* __restrict__ outp,
                                                   float* __restrict__ oPart,
                                                   float* __restrict__ mPart,
                                                   float* __restrict__ lPart)
{
  __shared__ __align__(16) ushort Ks[64 * 64];
  __shared__ __align__(16) ushort Vt[64 * 64];
  __shared__ __align__(16) ushort Ps[4][16 * 40];

  const int tid = threadIdx.x;
  const int w = tid >> 6, lane = tid & 63;
  const int lrow = lane & 15, lg = lane >> 4;

  const int bid = (blockIdx.x & 7) * 368 + (blockIdx.x >> 3);
  int h, b, bx, kv_lo, kv_hi, chunk = 0;
  bool isGlobal;
  if (bid < 1024) {
    isGlobal = true; h = 0;
    chunk = bid >> 7;
    int qb = bid & 127;
    b = qb >> 5; bx = qb & 31;
    kv_lo = chunk * 256; kv_hi = kv_lo + 256;
  } else {
    isGlobal = false;
    int t = bid - 1024;
    h = 1 + (t >> 7);
    int qb = t & 127;
    b = qb >> 5; bx = qb & 31;
    kv_lo = bx * 64 - 128; if (kv_lo < 0) kv_lo = 0;
    kv_hi = bx * 64 + 192; if (kv_hi > 2048) kv_hi = 2048;
  }
  const int q0b = bx * 64;
  const int q0 = q0b + w * 16;
  const ushort* Qp = qkv + (size_t)b * 2048 * 3072 + h * 64;
  const ushort* Kp = Qp + 1024;
  const ushort* Vp = Qp + 2048;

  s16x8 qf0 = *(const s16x8*)(Qp + (size_t)(q0 + lrow) * 3072 + 8 * lg);
  s16x8 qf1 = *(const s16x8*)(Qp + (size_t)(q0 + lrow) * 3072 + 32 + 8 * lg);

  const f32x4 zero = {0.f, 0.f, 0.f, 0.f};
  f32x4 o[4];
  o[0] = zero; o[1] = zero; o[2] = zero; o[3] = zero;
  float mrun = -3e38f, lsum = 0.f;
  const int q_abs = q0 + lrow;
  const float SCL = 0.18033688011112042f;  // 1/8 * log2(e)

  const int sp = tid >> 3;
  const int sg = tid & 7;
  const int kr0 = tid >> 3;
  const int kc = tid & 7;
  const int vx = (lrow & 7) ^ (lrow >> 3);

  for (int kv = kv_lo; kv < kv_hi; kv += 64) {
    const bool needMask = !isGlobal && (kv < q0b - 64 || kv + 64 > q0b + 128);

    const ushort* vrow = Vp + (size_t)(kv + 2 * sp) * 3072 + 8 * sg;
    s16x8 vlo = *(const s16x8*)vrow;
    s16x8 vhi = *(const s16x8*)(vrow + 3072);

    __syncthreads();

    GLDS(Kp + (size_t)(kv + kr0) * 3072 + 8 * (kc ^ (kr0 & 7)), &Ks[w * 512]);
    GLDS(Kp + (size_t)(kv + 32 + kr0) * 3072 + 8 * (kc ^ (kr0 & 7)), &Ks[2048 + w * 512]);

#pragma unroll
    for (int j = 0; j < 8; j++) {
      const int d = 8 * sg + j;
      const int r = 2 * sp;
      uint pk = (uint)(ushort)vlo[j] | ((uint)(ushort)vhi[j] << 16);
      *(uint*)&Vt[d * 64 + ((((r >> 3) ^ j ^ sg) & 7) << 3) + (r & 7)] = pk;
    }
    __syncthreads();

#pragma unroll
    for (int s = 0; s < 2; s++) {
      const int kb = kv + 32 * s;
      const int rs = 32 * s;
      s16x8 kA0 = *(const s16x8*)&Ks[(rs + lrow) * 64      + ((( lg      ^ (lrow & 7)) & 7) << 3)];
      s16x8 kA1 = *(const s16x8*)&Ks[(rs + lrow) * 64      + ((((4 + lg) ^ (lrow & 7)) & 7) << 3)];
      s16x8 kB0 = *(const s16x8*)&Ks[(rs + 16 + lrow) * 64 + ((( lg      ^ (lrow & 7)) & 7) << 3)];
      s16x8 kB1 = *(const s16x8*)&Ks[(rs + 16 + lrow) * 64 + ((((4 + lg) ^ (lrow & 7)) & 7) << 3)];

      f32x4 sA = __builtin_amdgcn_mfma_f32_16x16x32_bf16(kA0, qf0, zero, 0, 0, 0);
      sA = __builtin_amdgcn_mfma_f32_16x16x32_bf16(kA1, qf1, sA, 0, 0, 0);
      f32x4 sB = __builtin_amdgcn_mfma_f32_16x16x32_bf16(kB0, qf0, zero, 0, 0, 0);
      sB = __builtin_amdgcn_mfma_f32_16x16x32_bf16(kB1, qf1, sB, 0, 0, 0);

      float pA[4], pB[4];
      float rowmax = -3e38f;
      if (needMask) {
#pragma unroll
        for (int i = 0; i < 4; i++) {
          int kaA = kb + 4 * lg + i;
          int dq = q_abs - kaA;
          float va = (dq <= 128 && dq >= -128) ? sA[i] * SCL : -1e30f;
          pA[i] = va; rowmax = fmaxf(rowmax, va);
          int dqb = dq - 16;
          float vb = (dqb <= 128 && dqb >= -128) ? sB[i] * SCL : -1e30f;
          pB[i] = vb; rowmax = fmaxf(rowmax, vb);
        }
      } else {
#pragma unroll
        for (int i = 0; i < 4; i++) {
          pA[i] = sA[i] * SCL; pB[i] = sB[i] * SCL;
          rowmax = fmaxf(rowmax, fmaxf(pA[i], pB[i]));
        }
      }
      rowmax = fmaxf(rowmax, __shfl_xor(rowmax, 16));
      rowmax = fmaxf(rowmax, __shfl_xor(rowmax, 32));

      if (!__all(rowmax <= mrun + 8.f)) {
        float mnew = fmaxf(mrun, rowmax);
        float alpha = exp2f(mrun - mnew);
        mrun = mnew;
        lsum *= alpha;
        float a0 = __shfl(alpha, 4 * lg + 0);
        float a1 = __shfl(alpha, 4 * lg + 1);
        float a2 = __shfl(alpha, 4 * lg + 2);
        float a3 = __shfl(alpha, 4 * lg + 3);
#pragma unroll
        for (int c = 0; c < 4; c++) {
          o[c][0] *= a0; o[c][1] *= a1; o[c][2] *= a2; o[c][3] *= a3;
        }
      }

      float rsum = 0.f;
      if (needMask) {
#pragma unroll
        for (int i = 0; i < 4; i++) {
          pA[i] = (pA[i] > -1e29f) ? exp2f(pA[i] - mrun) : 0.f;
          pB[i] = (pB[i] > -1e29f) ? exp2f(pB[i] - mrun) : 0.f;
          rsum += pA[i] + pB[i];
        }
      } else {
#pragma unroll
        for (int i = 0; i < 4; i++) {
          pA[i] = exp2f(pA[i] - mrun);
          pB[i] = exp2f(pB[i] - mrun);
          rsum += pA[i] + pB[i];
        }
      }
      rsum += __shfl_xor(rsum, 16);
      rsum += __shfl_xor(rsum, 32);
      lsum += rsum;

      {
        ushort* P = &Ps[w][lrow * 40];
        *(uint*)&P[4 * lg]      = (uint)f2bf(pA[0]) | ((uint)f2bf(pA[1]) << 16);
        *(uint*)&P[4 * lg + 2]  = (uint)f2bf(pA[2]) | ((uint)f2bf(pA[3]) << 16);
        *(uint*)&P[16 + 4 * lg] = (uint)f2bf(pB[0]) | ((uint)f2bf(pB[1]) << 16);
        *(uint*)&P[18 + 4 * lg] = (uint)f2bf(pB[2]) | ((uint)f2bf(pB[3]) << 16);
      }
      s16x8 paf = *(const s16x8*)&Ps[w][lrow * 40 + 8 * lg];

#pragma unroll
      for (int c = 0; c < 4; c++) {
        const int d = 16 * c + lrow;
        s16x8 vf = *(const s16x8*)&Vt[d * 64 + ((((4 * s + lg) ^ vx ^ (2 * c)) & 7) << 3)];
        o[c] = __builtin_amdgcn_mfma_f32_16x16x32_bf16(paf, vf, o[c], 0, 0, 0);
      }
    }
  }

  if (isGlobal) {
    const size_t rbase = (size_t)(chunk * 4 + b) * 2048 + q0;
    if (lg == 0) {
      mPart[rbase + lrow] = mrun;
      lPart[rbase + lrow] = lsum;
    }
#pragma unroll
    for (int c = 0; c < 4; c++)
#pragma unroll
      for (int i = 0; i < 4; i++)
        oPart[(rbase + 4 * lg + i) * 64 + 16 * c + lrow] = o[c][i];
  } else {
    float li0 = 1.f / __shfl(lsum, 4 * lg + 0);
    float li1 = 1.f / __shfl(lsum, 4 * lg + 1);
    float li2 = 1.f / __shfl(lsum, 4 * lg + 2);
    float li3 = 1.f / __shfl(lsum, 4 * lg + 3);
    size_t orow = (size_t)(b * 2048 + q0 + 4 * lg);
#pragma unroll
    for (int c = 0; c < 4; c++) {
      outp[(orow + 0) * 1024 + h * 64 + 16 * c + lrow] = f2bf(o[c][0] * li0);
      outp[(orow + 1) * 1024 + h * 64 + 16 * c + lrow] = f2bf(o[c][1] * li1);
      outp[(orow + 2) * 1024 + h * 64 + 16 * c + lrow] = f2bf(o[c][2] * li2);
      outp[(orow + 3) * 1024 + h * 64 + 16 * c + lrow] = f2bf(o[c][3] * li3);
    }
  }
}

// ---------------- combine global-head partials ----------------
__global__ __launch_bounds__(256) void combine_kernel(const float* __restrict__ oPart,
                                                      const float* __restrict__ mPart,
                                                      const float* __restrict__ lPart,
                                                      ushort* __restrict__ attno) {
  const int tid = threadIdx.x;
  const int row = blockIdx.x * 64 + (tid >> 2);
  const int d0 = (tid & 3) * 16;
  float m[8], l[8], M = -3e38f;
#pragma unroll
  for (int p = 0; p < 8; p++) {
    m[p] = mPart[p * 8192 + row];
    l[p] = lPart[p * 8192 + row];
    M = fmaxf(M, m[p]);
  }
  float L = 0.f, wgt[8];
#pragma unroll
  for (int p = 0; p < 8; p++) { wgt[p] = exp2f(m[p] - M); L += wgt[p] * l[p]; }
  float inv = 1.f / L;
  float acc[16];
#pragma unroll
  for (int j = 0; j < 16; j++) acc[j] = 0.f;
#pragma unroll
  for (int p = 0; p < 8; p++) {
    const float* op = oPart + ((size_t)p * 8192 + row) * 64 + d0;
    float wv = wgt[p];
#pragma unroll
    for (int j = 0; j < 16; j += 4) {
      float4 v = *(const float4*)(op + j);
      acc[j]     += wv * v.x; acc[j + 1] += wv * v.y;
      acc[j + 2] += wv * v.z; acc[j + 3] += wv * v.w;
    }
  }
  ushort* dst = attno + (size_t)row * 1024 + d0;
#pragma unroll
  for (int j = 0; j < 16; j++) dst[j] = f2bf(acc[j] * inv);
}

// ---------------- launch ----------------
extern "C" void kernel_launch(void* const* d_in, const int* in_sizes, int n_in,
                              void* d_out, int out_size, void* d_ws, size_t ws_size,
                              hipStream_t stream) {
  const float* x  = (const float*)d_in[0];
  const float* wq = (const float*)d_in[1];
  const float* bq = (const float*)d_in[2];
  const float* wk = (const float*)d_in[3];
  const float* bk = (const float*)d_in[4];
  const float* wv = (const float*)d_in[5];
  const float* bv = (const float*)d_in[6];
  const float* wo = (const float*)d_in[7];
  const float* bo = (const float*)d_in[8];

  char* ws = (char*)d_ws;
  ushort* xb    = (ushort*)(ws);                 // 8192x1024 bf16 = 16 MB
  ushort* wqkvb = (ushort*)(ws + 16777216);      // 3072x1024 bf16 =  6 MB
  ushort* wob   = (ushort*)(ws + 23068672);      // 1024x1024 bf16 =  2 MB
  ushort* qkvb  = (ushort*)(ws + 25165824);      // 8192x3072 bf16 = 48 MB
  ushort* attno = (ushort*)(ws + 75497472);      // 8192x1024 bf16 = 16 MB
  float* oPart = (float*)(ws);                   // 8x8192x64 f32 = 16 MB (over xb)
  float* mPart = (float*)(ws + 16777216);
  float* lPart = (float*)(ws + 16777216 + 262144);

  castk<<<8192, 256, 0, stream>>>(x, xb, 8388608);
  castw<<<4096, 256, 0, stream>>>(wq, wk, wv, wo,
                                  wqkvb, wqkvb + 1048576, wqkvb + 2097152, wob);

  // QKV projection: [8192,3072] = xb * wqkvb^T ; grid 64x12 = 768 blocks
  gemm256<1><<<768, 512, 0, stream>>>(xb, wqkvb, bq, bk, bv,
                                      (void*)qkvb, 8192, 3072, 1024, 12);

  attn_kernel<<<2944, 256, 0, stream>>>(qkvb, attno, oPart, mPart, lPart);
  combine_kernel<<<128, 256, 0, stream>>>(oPart, mPart, lPart, attno);

  // output projection: grid 64x4 = 256 blocks, f32 out
  gemm256<0><<<256, 512, 0, stream>>>(attno, wob, bo, nullptr, nullptr,
                                      (void*)d_out, 8192, 1024, 1024, 4);
}

// Round 6
// 161.392 us; speedup vs baseline: 2.0101x; 1.0259x over previous
//
#include <hip/hip_runtime.h>

typedef __attribute__((ext_vector_type(4))) float f32x4;
typedef __attribute__((ext_vector_type(8))) short s16x8;

#define GLDS(gsrc, ldst) \
  __builtin_amdgcn_global_load_lds((const __attribute__((address_space(1))) void*)(gsrc), \
                                   (__attribute__((address_space(3))) void*)(ldst), 16, 0, 0)

__device__ __forceinline__ ushort f2bf(float f) {
  union { float f; unsigned u; } x; x.f = f;
  unsigned r = (x.u + 0x7FFFu + ((x.u >> 16) & 1u)) >> 16;
  return (ushort)r;
}

template<int N> __device__ __forceinline__ void waitvm() {
  if constexpr (N == 0) asm volatile("s_waitcnt vmcnt(0)" ::: "memory");
  else if constexpr (N == 6) asm volatile("s_waitcnt vmcnt(6)" ::: "memory");
  else if constexpr (N == 7) asm volatile("s_waitcnt vmcnt(7)" ::: "memory");
  else if constexpr (N == 8) asm volatile("s_waitcnt vmcnt(8)" ::: "memory");
}

// ---------------- cast f32 -> bf16 (vectorized) ----------------
__global__ __launch_bounds__(256) void castk(const float* __restrict__ in,
                                             ushort* __restrict__ outp, int n) {
  int i = (blockIdx.x * 256 + threadIdx.x) * 4;
  if (i >= n) return;
  float4 v = *(const float4*)(in + i);
  ushort4 r;
  r.x = f2bf(v.x); r.y = f2bf(v.y); r.z = f2bf(v.z); r.w = f2bf(v.w);
  *(ushort4*)(outp + i) = r;
}

__global__ __launch_bounds__(256) void castw(const float* __restrict__ w0, const float* __restrict__ w1,
                                             const float* __restrict__ w2, const float* __restrict__ w3,
                                             ushort* __restrict__ o0, ushort* __restrict__ o1,
                                             ushort* __restrict__ o2, ushort* __restrict__ o3) {
  int bid = blockIdx.x;
  int sel = bid >> 10;
  const float* in = (sel == 0) ? w0 : (sel == 1) ? w1 : (sel == 2) ? w2 : w3;
  ushort* outp    = (sel == 0) ? o0 : (sel == 1) ? o1 : (sel == 2) ? o2 : o3;
  int i = ((bid & 1023) * 256 + threadIdx.x) * 4;
  float4 v = *(const float4*)(in + i);
  ushort4 r;
  r.x = f2bf(v.x); r.y = f2bf(v.y); r.z = f2bf(v.z); r.w = f2bf(v.w);
  *(ushort4*)(outp + i) = r;
}

// ---------------- GEMM, phased schedule ----------------
// C[M,N] = A[M,K]*Bt[N,K]^T + bias.  BM=32*MREP, BN=64*NREP. 512 thr = 8 waves (2M x 4N).
// Per-wave output: (16*MREP) x (16*NREP). K-tile = 64, double-buffered LDS.
// Swizzle: 16B granule g of row r stored at slot g^(r&7) (involution, both sides).
// Counted vmcnt(TOT) at iteration entry only; stages issued after the pre-MFMA
// barrier of the phase where the target region is dead.
template<int MREP, int NREP, int OUTBF16>
__global__ __launch_bounds__(512) void gemm8p(
    const ushort* __restrict__ A, const ushort* __restrict__ Bt,
    const float* __restrict__ bias0, const float* __restrict__ bias1,
    const float* __restrict__ bias2,
    void* __restrict__ Cout, int M, int N, int K, int nxn)
{
  constexpr int BM = 32 * MREP;
  constexpr int BN = 64 * NREP;
  constexpr int AUS = BM * 64;          // A ushorts per buffer
  constexpr int SBUF = (BM + BN) * 64;  // buffer stride in ushorts
  constexpr int IA = BM / 64;           // global_load_lds issues per tile (A)
  constexpr int IB = BN / 64;
  constexpr int TOT = IA + IB;

  __shared__ __align__(16) ushort lds[2 * SBUF];

  const int tid = threadIdx.x;
  const int w = tid >> 6, lane = tid & 63;
  const int lrow = lane & 15, lg = lane >> 4;
  const int wm = w >> 2, wn = w & 3;
  const int cpx = gridDim.x >> 3;
  const int wgid = ((int)blockIdx.x & 7) * cpx + ((int)blockIdx.x >> 3);
  const int mblk = (wgid / nxn) * BM;
  const int nblk = (wgid % nxn) * BN;
  const int NT = K >> 6;

  // staging: thread covers rows {R*64 + (tid>>3)}, source granule pre-swizzled
  const int srow = tid >> 3;
  const int sg8 = 8 * ((tid & 7) ^ (srow & 7));
  const ushort* Ab = A + (size_t)(mblk + srow) * K + sg8;
  const ushort* Bb = Bt + (size_t)(nblk + srow) * K + sg8;
  const size_t rstep = (size_t)64 * K;

  auto stageA = [&](const ushort* p, int dst) {
#pragma unroll
    for (int R = 0; R < IA; R++)
      GLDS(p + (size_t)R * rstep, &lds[dst + R * 4096 + w * 512]);
  };
  auto stageB = [&](const ushort* p, int dst) {
#pragma unroll
    for (int R = 0; R < IB; R++)
      GLDS(p + (size_t)R * rstep, &lds[dst + AUS + R * 4096 + w * 512]);
  };

  // fragment read bases (ushort idx within buffer); row&7 == lrow&7
  const int xs0 = (lg ^ (lrow & 7)) << 3;
  const int xs1 = ((4 + lg) ^ (lrow & 7)) << 3;
  const int laneA0 = (wm * (BM / 2) + lrow) * 64 + xs0;
  const int laneA1 = (wm * (BM / 2) + lrow) * 64 + xs1;
  const int laneB0 = AUS + (wn * (16 * NREP) + lrow) * 64 + xs0;
  const int laneB1 = AUS + (wn * (16 * NREP) + lrow) * 64 + xs1;

  const f32x4 zero = {0.f, 0.f, 0.f, 0.f};
  f32x4 acc[MREP][NREP];
#pragma unroll
  for (int m = 0; m < MREP; m++)
#pragma unroll
    for (int n = 0; n < NREP; n++) acc[m][n] = zero;

  // prologue: tile 0 -> buf 0, tile 1 -> buf 1
  stageA(Ab, 0);       stageB(Bb, 0);
  stageA(Ab + 64, SBUF); stageB(Bb + 64, SBUF);
  const ushort* aN = Ab + 128;
  const ushort* bN = Bb + 128;

  int bb = 0;
  for (int t = 0; t < NT; ++t) {
    if (t < NT - 1) waitvm<TOT>(); else waitvm<0>();
    __builtin_amdgcn_s_barrier();
    const bool pf = (t + 2 < NT);

    if constexpr (MREP == 8) {
      s16x8 af[4], bfr[NREP];
      // ph0: mh0 kk0
#pragma unroll
      for (int j = 0; j < 4; j++) af[j] = *(const s16x8*)&lds[bb + laneA0 + j * 1024];
#pragma unroll
      for (int n = 0; n < NREP; n++) bfr[n] = *(const s16x8*)&lds[bb + laneB0 + n * 1024];
      __builtin_amdgcn_s_barrier();
      __builtin_amdgcn_s_setprio(1);
#pragma unroll
      for (int j = 0; j < 4; j++)
#pragma unroll
        for (int n = 0; n < NREP; n++)
          acc[j][n] = __builtin_amdgcn_mfma_f32_16x16x32_bf16(af[j], bfr[n], acc[j][n], 0, 0, 0);
      __builtin_amdgcn_s_setprio(0);
      __builtin_amdgcn_s_barrier();
      // ph1: mh1 kk0
#pragma unroll
      for (int j = 0; j < 4; j++) af[j] = *(const s16x8*)&lds[bb + laneA0 + (4 + j) * 1024];
      __builtin_amdgcn_s_barrier();
      __builtin_amdgcn_s_setprio(1);
#pragma unroll
      for (int j = 0; j < 4; j++)
#pragma unroll
        for (int n = 0; n < NREP; n++)
          acc[4 + j][n] = __builtin_amdgcn_mfma_f32_16x16x32_bf16(af[j], bfr[n], acc[4 + j][n], 0, 0, 0);
      __builtin_amdgcn_s_setprio(0);
      __builtin_amdgcn_s_barrier();
      // ph2: mh0 kk1  (+stage B of tile t+2: B region of buf bb now dead)
#pragma unroll
      for (int j = 0; j < 4; j++) af[j] = *(const s16x8*)&lds[bb + laneA1 + j * 1024];
#pragma unroll
      for (int n = 0; n < NREP; n++) bfr[n] = *(const s16x8*)&lds[bb + laneB1 + n * 1024];
      __builtin_amdgcn_s_barrier();
      if (pf) stageB(bN, bb);
      __builtin_amdgcn_s_setprio(1);
#pragma unroll
      for (int j = 0; j < 4; j++)
#pragma unroll
        for (int n = 0; n < NREP; n++)
          acc[j][n] = __builtin_amdgcn_mfma_f32_16x16x32_bf16(af[j], bfr[n], acc[j][n], 0, 0, 0);
      __builtin_amdgcn_s_setprio(0);
      __builtin_amdgcn_s_barrier();
      // ph3: mh1 kk1  (+stage A of tile t+2: A region now dead)
#pragma unroll
      for (int j = 0; j < 4; j++) af[j] = *(const s16x8*)&lds[bb + laneA1 + (4 + j) * 1024];
      __builtin_amdgcn_s_barrier();
      if (pf) stageA(aN, bb);
      __builtin_amdgcn_s_setprio(1);
#pragma unroll
      for (int j = 0; j < 4; j++)
#pragma unroll
        for (int n = 0; n < NREP; n++)
          acc[4 + j][n] = __builtin_amdgcn_mfma_f32_16x16x32_bf16(af[j], bfr[n], acc[4 + j][n], 0, 0, 0);
      __builtin_amdgcn_s_setprio(0);
    } else {
      s16x8 af[4], bfr[NREP];
      // ph0: kk0
#pragma unroll
      for (int j = 0; j < 4; j++) af[j] = *(const s16x8*)&lds[bb + laneA0 + j * 1024];
#pragma unroll
      for (int n = 0; n < NREP; n++) bfr[n] = *(const s16x8*)&lds[bb + laneB0 + n * 1024];
      __builtin_amdgcn_s_barrier();
      __builtin_amdgcn_s_setprio(1);
#pragma unroll
      for (int j = 0; j < 4; j++)
#pragma unroll
        for (int n = 0; n < NREP; n++)
          acc[j][n] = __builtin_amdgcn_mfma_f32_16x16x32_bf16(af[j], bfr[n], acc[j][n], 0, 0, 0);
      __builtin_amdgcn_s_setprio(0);
      __builtin_amdgcn_s_barrier();
      // ph1: kk1 (+stage both: whole buf bb dead after these reads)
#pragma unroll
      for (int j = 0; j < 4; j++) af[j] = *(const s16x8*)&lds[bb + laneA1 + j * 1024];
#pragma unroll
      for (int n = 0; n < NREP; n++) bfr[n] = *(const s16x8*)&lds[bb + laneB1 + n * 1024];
      __builtin_amdgcn_s_barrier();
      if (pf) { stageA(aN, bb); stageB(bN, bb); }
      __builtin_amdgcn_s_setprio(1);
#pragma unroll
      for (int j = 0; j < 4; j++)
#pragma unroll
        for (int n = 0; n < NREP; n++)
          acc[j][n] = __builtin_amdgcn_mfma_f32_16x16x32_bf16(af[j], bfr[n], acc[j][n], 0, 0, 0);
      __builtin_amdgcn_s_setprio(0);
    }

    if (pf) { aN += 64; bN += 64; }
    bb ^= SBUF;
  }

  // bias per n-fragment column
  float bias_n[NREP];
#pragma unroll
  for (int n = 0; n < NREP; n++) {
    const int col = nblk + wn * (16 * NREP) + n * 16 + lrow;
    if (bias1) bias_n[n] = (col < 1024) ? bias0[col]
                          : (col < 2048 ? bias1[col - 1024] : bias2[col - 2048]);
    else bias_n[n] = bias0[col];
  }

  if constexpr (OUTBF16) {
    __syncthreads();
    ushort* Ct = lds;   // [BM][BN] bf16
#pragma unroll
    for (int m = 0; m < MREP; m++)
#pragma unroll
      for (int n = 0; n < NREP; n++) {
        f32x4 v = acc[m][n];
#pragma unroll
        for (int i = 0; i < 4; i++)
          Ct[(wm * (BM / 2) + m * 16 + 4 * lg + i) * BN + wn * (16 * NREP) + n * 16 + lrow] =
              f2bf(v[i] + bias_n[n]);
      }
    __syncthreads();
    ushort* Cg = (ushort*)Cout;
    constexpr int GR = BM * BN / 8;
#pragma unroll
    for (int p = 0; p < GR / 512; p++) {
      unsigned g = p * 512 + tid;
      unsigned row = g / (BN / 8);
      unsigned cg = g % (BN / 8);
      *(s16x8*)&Cg[(size_t)(mblk + row) * N + nblk + cg * 8] = *(const s16x8*)&lds[g * 8];
    }
  } else {
    // f32 out, two 64-row chunks through LDS (MREP==4 path)
    float* Cf = (float*)lds;   // [64][BN]
    float* Cg = (float*)Cout;
#pragma unroll
    for (int ch = 0; ch < 2; ch++) {
      __syncthreads();
      if (wm == ch) {
#pragma unroll
        for (int m = 0; m < MREP; m++)
#pragma unroll
          for (int n = 0; n < NREP; n++) {
            f32x4 v = acc[m][n];
#pragma unroll
            for (int i = 0; i < 4; i++)
              Cf[(m * 16 + 4 * lg + i) * BN + wn * (16 * NREP) + n * 16 + lrow] = v[i] + bias_n[n];
          }
      }
      __syncthreads();
#pragma unroll
      for (int p = 0; p < (64 * BN / 4) / 512; p++) {
        unsigned fg = p * 512 + tid;
        unsigned row = fg / (BN / 4);
        unsigned c4 = fg % (BN / 4);
        *(float4*)&Cg[(size_t)(mblk + ch * 64 + row) * N + nblk + c4 * 4] =
            *(const float4*)&Cf[row * BN + c4 * 4];
      }
    }
  }
}

// ---------------- banded / global flash attention (balanced) ----------------
__global__ __launch_bounds__(256) void attn_kernel(const ushort* __restrict__ qkv,
                                                   ushort* __restrict__ outp,
                                                   float* __restrict__ oPart,
                                                   float* __restrict__ mPart,
                                                   float* __restrict__ lPart)
{
  __shared__ __align__(16) ushort Ks[64 * 64];
  __shared__ __align__(16) ushort Vt[64 * 64];
  __shared__ __align__(16) ushort Ps[4][16 * 40];

  const int tid = threadIdx.x;
  const int w = tid >> 6, lane = tid & 63;
  const int lrow = lane & 15, lg = lane >> 4;

  const int bid = (blockIdx.x & 7) * 368 + (blockIdx.x >> 3);
  int h, b, bx, kv_lo, kv_hi, chunk = 0;
  bool isGlobal;
  if (bid < 1024) {
    isGlobal = true; h = 0;
    chunk = bid >> 7;
    int qb = bid & 127;
    b = qb >> 5; bx = qb & 31;
    kv_lo = chunk * 256; kv_hi = kv_lo + 256;
  } else {
    isGlobal = false;
    int t = bid - 1024;
    h = 1 + (t >> 7);
    int qb = t & 127;
    b = qb >> 5; bx = qb & 31;
    kv_lo = bx * 64 - 128; if (kv_lo < 0) kv_lo = 0;
    kv_hi = bx * 64 + 192; if (kv_hi > 2048) kv_hi = 2048;
  }
  const int q0b = bx * 64;
  const int q0 = q0b + w * 16;
  const ushort* Qp = qkv + (size_t)b * 2048 * 3072 + h * 64;
  const ushort* Kp = Qp + 1024;
  const ushort* Vp = Qp + 2048;

  s16x8 qf0 = *(const s16x8*)(Qp + (size_t)(q0 + lrow) * 3072 + 8 * lg);
  s16x8 qf1 = *(const s16x8*)(Qp + (size_t)(q0 + lrow) * 3072 + 32 + 8 * lg);

  const f32x4 zero = {0.f, 0.f, 0.f, 0.f};
  f32x4 o[4];
  o[0] = zero; o[1] = zero; o[2] = zero; o[3] = zero;
  float mrun = -3e38f, lsum = 0.f;
  const int q_abs = q0 + lrow;
  const float SCL = 0.18033688011112042f;  // 1/8 * log2(e)

  const int sp = tid >> 3;
  const int sg = tid & 7;
  const int kr0 = tid >> 3;
  const int kc = tid & 7;
  const int vx = (lrow & 7) ^ (lrow >> 3);

  for (int kv = kv_lo; kv < kv_hi; kv += 64) {
    const bool needMask = !isGlobal && (kv < q0b - 64 || kv + 64 > q0b + 128);

    const ushort* vrow = Vp + (size_t)(kv + 2 * sp) * 3072 + 8 * sg;
    s16x8 vlo = *(const s16x8*)vrow;
    s16x8 vhi = *(const s16x8*)(vrow + 3072);

    __syncthreads();

    GLDS(Kp + (size_t)(kv + kr0) * 3072 + 8 * (kc ^ (kr0 & 7)), &Ks[w * 512]);
    GLDS(Kp + (size_t)(kv + 32 + kr0) * 3072 + 8 * (kc ^ (kr0 & 7)), &Ks[2048 + w * 512]);

#pragma unroll
    for (int j = 0; j < 8; j++) {
      const int d = 8 * sg + j;
      const int r = 2 * sp;
      uint pk = (uint)(ushort)vlo[j] | ((uint)(ushort)vhi[j] << 16);
      *(uint*)&Vt[d * 64 + ((((r >> 3) ^ j ^ sg) & 7) << 3) + (r & 7)] = pk;
    }
    __syncthreads();

#pragma unroll
    for (int s = 0; s < 2; s++) {
      const int kb = kv + 32 * s;
      const int rs = 32 * s;
      s16x8 kA0 = *(const s16x8*)&Ks[(rs + lrow) * 64      + ((( lg      ^ (lrow & 7)) & 7) << 3)];
      s16x8 kA1 = *(const s16x8*)&Ks[(rs + lrow) * 64      + ((((4 + lg) ^ (lrow & 7)) & 7) << 3)];
      s16x8 kB0 = *(const s16x8*)&Ks[(rs + 16 + lrow) * 64 + ((( lg      ^ (lrow & 7)) & 7) << 3)];
      s16x8 kB1 = *(const s16x8*)&Ks[(rs + 16 + lrow) * 64 + ((((4 + lg) ^ (lrow & 7)) & 7) << 3)];

      f32x4 sA = __builtin_amdgcn_mfma_f32_16x16x32_bf16(kA0, qf0, zero, 0, 0, 0);
      sA = __builtin_amdgcn_mfma_f32_16x16x32_bf16(kA1, qf1, sA, 0, 0, 0);
      f32x4 sB = __builtin_amdgcn_mfma_f32_16x16x32_bf16(kB0, qf0, zero, 0, 0, 0);
      sB = __builtin_amdgcn_mfma_f32_16x16x32_bf16(kB1, qf1, sB, 0, 0, 0);

      float pA[4], pB[4];
      float rowmax = -3e38f;
      if (needMask) {
#pragma unroll
        for (int i = 0; i < 4; i++) {
          int kaA = kb + 4 * lg + i;
          int dq = q_abs - kaA;
          float va = (dq <= 128 && dq >= -128) ? sA[i] * SCL : -1e30f;
          pA[i] = va; rowmax = fmaxf(rowmax, va);
          int dqb = dq - 16;
          float vb = (dqb <= 128 && dqb >= -128) ? sB[i] * SCL : -1e30f;
          pB[i] = vb; rowmax = fmaxf(rowmax, vb);
        }
      } else {
#pragma unroll
        for (int i = 0; i < 4; i++) {
          pA[i] = sA[i] * SCL; pB[i] = sB[i] * SCL;
          rowmax = fmaxf(rowmax, fmaxf(pA[i], pB[i]));
        }
      }
      rowmax = fmaxf(rowmax, __shfl_xor(rowmax, 16));
      rowmax = fmaxf(rowmax, __shfl_xor(rowmax, 32));

      if (!__all(rowmax <= mrun + 8.f)) {
        float mnew = fmaxf(mrun, rowmax);
        float alpha = exp2f(mrun - mnew);
        mrun = mnew;
        lsum *= alpha;
        float a0 = __shfl(alpha, 4 * lg + 0);
        float a1 = __shfl(alpha, 4 * lg + 1);
        float a2 = __shfl(alpha, 4 * lg + 2);
        float a3 = __shfl(alpha, 4 * lg + 3);
#pragma unroll
        for (int c = 0; c < 4; c++) {
          o[c][0] *= a0; o[c][1] *= a1; o[c][2] *= a2; o[c][3] *= a3;
        }
      }

      float rsum = 0.f;
      if (needMask) {
#pragma unroll
        for (int i = 0; i < 4; i++) {
          pA[i] = (pA[i] > -1e29f) ? exp2f(pA[i] - mrun) : 0.f;
          pB[i] = (pB[i] > -1e29f) ? exp2f(pB[i] - mrun) : 0.f;
          rsum += pA[i] + pB[i];
        }
      } else {
#pragma unroll
        for (int i = 0; i < 4; i++) {
          pA[i] = exp2f(pA[i] - mrun);
          pB[i] = exp2f(pB[i] - mrun);
          rsum += pA[i] + pB[i];
        }
      }
      rsum += __shfl_xor(rsum, 16);
      rsum += __shfl_xor(rsum, 32);
      lsum += rsum;

      {
        ushort* P = &Ps[w][lrow * 40];
        *(uint*)&P[4 * lg]      = (uint)f2bf(pA[0]) | ((uint)f2bf(pA[1]) << 16);
        *(uint*)&P[4 * lg + 2]  = (uint)f2bf(pA[2]) | ((uint)f2bf(pA[3]) << 16);
        *(uint*)&P[16 + 4 * lg] = (uint)f2bf(pB[0]) | ((uint)f2bf(pB[1]) << 16);
        *(uint*)&P[18 + 4 * lg] = (uint)f2bf(pB[2]) | ((uint)f2bf(pB[3]) << 16);
      }
      s16x8 paf = *(const s16x8*)&Ps[w][lrow * 40 + 8 * lg];

#pragma unroll
      for (int c = 0; c < 4; c++) {
        const int d = 16 * c + lrow;
        s16x8 vf = *(const s16x8*)&Vt[d * 64 + ((((4 * s + lg) ^ vx ^ (2 * c)) & 7) << 3)];
        o[c] = __builtin_amdgcn_mfma_f32_16x16x32_bf16(paf, vf, o[c], 0, 0, 0);
      }
    }
  }

  if (isGlobal) {
    const size_t rbase = (size_t)(chunk * 4 + b) * 2048 + q0;
    if (lg == 0) {
      mPart[rbase + lrow] = mrun;
      lPart[rbase + lrow] = lsum;
    }
#pragma unroll
    for (int c = 0; c < 4; c++)
#pragma unroll
      for (int i = 0; i < 4; i++)
        oPart[(rbase + 4 * lg + i) * 64 + 16 * c + lrow] = o[c][i];
  } else {
    float li0 = 1.f / __shfl(lsum, 4 * lg + 0);
    float li1 = 1.f / __shfl(lsum, 4 * lg + 1);
    float li2 = 1.f / __shfl(lsum, 4 * lg + 2);
    float li3 = 1.f / __shfl(lsum, 4 * lg + 3);
    size_t orow = (size_t)(b * 2048 + q0 + 4 * lg);
#pragma unroll
    for (int c = 0; c < 4; c++) {
      outp[(orow + 0) * 1024 + h * 64 + 16 * c + lrow] = f2bf(o[c][0] * li0);
      outp[(orow + 1) * 1024 + h * 64 + 16 * c + lrow] = f2bf(o[c][1] * li1);
      outp[(orow + 2) * 1024 + h * 64 + 16 * c + lrow] = f2bf(o[c][2] * li2);
      outp[(orow + 3) * 1024 + h * 64 + 16 * c + lrow] = f2bf(o[c][3] * li3);
    }
  }
}

// ---------------- combine global-head partials ----------------
__global__ __launch_bounds__(256) void combine_kernel(const float* __restrict__ oPart,
                                                      const float* __restrict__ mPart,
                                                      const float* __restrict__ lPart,
                                                      ushort* __restrict__ attno) {
  const int tid = threadIdx.x;
  const int row = blockIdx.x * 64 + (tid >> 2);
  const int d0 = (tid & 3) * 16;
  float m[8], l[8], M = -3e38f;
#pragma unroll
  for (int p = 0; p < 8; p++) {
    m[p] = mPart[p * 8192 + row];
    l[p] = lPart[p * 8192 + row];
    M = fmaxf(M, m[p]);
  }
  float L = 0.f, wgt[8];
#pragma unroll
  for (int p = 0; p < 8; p++) { wgt[p] = exp2f(m[p] - M); L += wgt[p] * l[p]; }
  float inv = 1.f / L;
  float acc[16];
#pragma unroll
  for (int j = 0; j < 16; j++) acc[j] = 0.f;
#pragma unroll
  for (int p = 0; p < 8; p++) {
    const float* op = oPart + ((size_t)p * 8192 + row) * 64 + d0;
    float wv = wgt[p];
#pragma unroll
    for (int j = 0; j < 16; j += 4) {
      float4 v = *(const float4*)(op + j);
      acc[j]     += wv * v.x; acc[j + 1] += wv * v.y;
      acc[j + 2] += wv * v.z; acc[j + 3] += wv * v.w;
    }
  }
  ushort* dst = attno + (size_t)row * 1024 + d0;
#pragma unroll
  for (int j = 0; j < 16; j++) dst[j] = f2bf(acc[j] * inv);
}

// ---------------- launch ----------------
extern "C" void kernel_launch(void* const* d_in, const int* in_sizes, int n_in,
                              void* d_out, int out_size, void* d_ws, size_t ws_size,
                              hipStream_t stream) {
  const float* x  = (const float*)d_in[0];
  const float* wq = (const float*)d_in[1];
  const float* bq = (const float*)d_in[2];
  const float* wk = (const float*)d_in[3];
  const float* bk = (const float*)d_in[4];
  const float* wv = (const float*)d_in[5];
  const float* bv = (const float*)d_in[6];
  const float* wo = (const float*)d_in[7];
  const float* bo = (const float*)d_in[8];

  char* ws = (char*)d_ws;
  ushort* xb    = (ushort*)(ws);                 // 8192x1024 bf16 = 16 MB
  ushort* wqkvb = (ushort*)(ws + 16777216);      // 3072x1024 bf16 =  6 MB
  ushort* wob   = (ushort*)(ws + 23068672);      // 1024x1024 bf16 =  2 MB
  ushort* qkvb  = (ushort*)(ws + 25165824);      // 8192x3072 bf16 = 48 MB
  ushort* attno = (ushort*)(ws + 75497472);      // 8192x1024 bf16 = 16 MB
  float* oPart = (float*)(ws);                   // 8x8192x64 f32 = 16 MB (over xb)
  float* mPart = (float*)(ws + 16777216);
  float* lPart = (float*)(ws + 16777216 + 262144);

  castk<<<8192, 256, 0, stream>>>(x, xb, 8388608);
  castw<<<4096, 256, 0, stream>>>(wq, wk, wv, wo,
                                  wqkvb, wqkvb + 1048576, wqkvb + 2097152, wob);

  // QKV projection: [8192,3072]; BM=256,BN=192 -> grid 32x16 = 512 blocks (2 exact rounds)
  gemm8p<8, 3, 1><<<512, 512, 0, stream>>>(xb, wqkvb, bq, bk, bv,
                                           (void*)qkvb, 8192, 3072, 1024, 16);

  attn_kernel<<<2944, 256, 0, stream>>>(qkvb, attno, oPart, mPart, lPart);
  combine_kernel<<<128, 256, 0, stream>>>(oPart, mPart, lPart, attno);

  // output projection: BM=128,BN=256 -> grid 64x4 = 256 blocks (1 round), f32 out
  gemm8p<4, 4, 0><<<256, 512, 0, stream>>>(attno, wob, bo, nullptr, nullptr,
                                           (void*)d_out, 8192, 1024, 1024, 4);
}